// Round 3
// baseline (703.992 us; speedup 1.0000x reference)
//
#include <hip/hip_runtime.h>
#include <math.h>

#define Bq 64
#define Lq 256
#define Eq 300
#define Hq 128
#define MQ (Bq*Lq)   // 16384

#define LRELU_S 0.2f

__device__ __forceinline__ float lrelu(float x) { return x > 0.f ? x : LRELU_S * x; }

// ---------------------------------------------------------------------------
// Generic tiled GEMM: C[m,n] = sum_k A[m,k]*W[n,k] (+ bias[n])
// A row m is emb[ids[m],:] if ids != nullptr, else Asrc[m,:]
// ---------------------------------------------------------------------------
#define BM 64
#define BN 64
#define BK 16

__global__ __launch_bounds__(256) void gemm_awt(
    const float* __restrict__ Asrc, const int* __restrict__ ids,
    const float* __restrict__ W, const float* __restrict__ bias,
    float* __restrict__ C, int M, int N, int K)
{
  __shared__ float As[BK][BM + 4];
  __shared__ float Bs[BK][BN + 4];
  int tid = threadIdx.x;
  int tx = tid & 15, ty = tid >> 4;
  int row0 = blockIdx.x * BM, col0 = blockIdx.y * BN;

  int lrow = tid >> 2;          // 0..63
  int lk   = (tid & 3) << 2;    // 0,4,8,12

  const float* Arow;
  {
    int r = row0 + lrow;
    int id = ids ? ids[r] : r;
    Arow = Asrc + (size_t)id * K;
  }
  const float* Wrow = W + (size_t)(col0 + lrow) * K;

  float acc[4][4] = {};

  for (int k0 = 0; k0 < K; k0 += BK) {
    int kk = k0 + lk;
    float4 av, bv;
    if (kk + 3 < K) {
      av = *(const float4*)(Arow + kk);
      bv = *(const float4*)(Wrow + kk);
    } else {
      float a0 = (kk + 0 < K) ? Arow[kk + 0] : 0.f;
      float a1 = (kk + 1 < K) ? Arow[kk + 1] : 0.f;
      float a2 = (kk + 2 < K) ? Arow[kk + 2] : 0.f;
      float a3 = (kk + 3 < K) ? Arow[kk + 3] : 0.f;
      av = make_float4(a0, a1, a2, a3);
      float b0 = (kk + 0 < K) ? Wrow[kk + 0] : 0.f;
      float b1 = (kk + 1 < K) ? Wrow[kk + 1] : 0.f;
      float b2 = (kk + 2 < K) ? Wrow[kk + 2] : 0.f;
      float b3 = (kk + 3 < K) ? Wrow[kk + 3] : 0.f;
      bv = make_float4(b0, b1, b2, b3);
    }
    As[lk + 0][lrow] = av.x; As[lk + 1][lrow] = av.y;
    As[lk + 2][lrow] = av.z; As[lk + 3][lrow] = av.w;
    Bs[lk + 0][lrow] = bv.x; Bs[lk + 1][lrow] = bv.y;
    Bs[lk + 2][lrow] = bv.z; Bs[lk + 3][lrow] = bv.w;
    __syncthreads();

    #pragma unroll
    for (int k = 0; k < BK; ++k) {
      float4 a4 = *(const float4*)&As[k][ty * 4];
      float4 b4 = *(const float4*)&Bs[k][tx * 4];
      float a[4] = {a4.x, a4.y, a4.z, a4.w};
      float bb[4] = {b4.x, b4.y, b4.z, b4.w};
      #pragma unroll
      for (int i = 0; i < 4; ++i)
        #pragma unroll
        for (int j = 0; j < 4; ++j)
          acc[i][j] += a[i] * bb[j];
    }
    __syncthreads();
  }

  #pragma unroll
  for (int i = 0; i < 4; ++i) {
    int r = row0 + ty * 4 + i;
    #pragma unroll
    for (int j = 0; j < 4; ++j) {
      int cidx = col0 + tx * 4 + j;
      float v = acc[i][j] + (bias ? bias[cidx] : 0.f);
      C[(size_t)r * N + cidx] = v;
    }
  }
}

// ---------------------------------------------------------------------------
// Fused gates GEMM: C[m, 0:512] = emb[ids[m]] @ Wih_f^T + b_f
//                   C[m, 512:1024] = emb[ids[m]] @ Wih_b^T + b_b
// A-tile (gathered emb rows) loaded once for both weight sets.
// ---------------------------------------------------------------------------
__global__ __launch_bounds__(256) void gemm_gates(
    const float* __restrict__ emb, const int* __restrict__ ids,
    const float* __restrict__ Wf, const float* __restrict__ bf,
    const float* __restrict__ Wb, const float* __restrict__ bb_,
    float* __restrict__ C)
{
  const int K = Eq;
  __shared__ float As[BK][BM + 4];
  __shared__ float Bs[BK][BN + 4];
  int tid = threadIdx.x;
  int tx = tid & 15, ty = tid >> 4;
  int row0 = blockIdx.x * BM, col0 = blockIdx.y * BN;   // col0 in 0..960

  int lrow = tid >> 2;
  int lk   = (tid & 3) << 2;

  const float* W    = (col0 < 512) ? Wf : Wb;
  const float* bias = (col0 < 512) ? bf : bb_;
  int wcol0 = col0 & 511;

  const float* Arow = emb + (size_t)ids[row0 + lrow] * K;
  const float* Wrow = W + (size_t)(wcol0 + lrow) * K;

  float acc[4][4] = {};

  for (int k0 = 0; k0 < K; k0 += BK) {
    int kk = k0 + lk;
    float4 av, bv;
    if (kk + 3 < K) {
      av = *(const float4*)(Arow + kk);
      bv = *(const float4*)(Wrow + kk);
    } else {
      float a0 = (kk + 0 < K) ? Arow[kk + 0] : 0.f;
      float a1 = (kk + 1 < K) ? Arow[kk + 1] : 0.f;
      float a2 = (kk + 2 < K) ? Arow[kk + 2] : 0.f;
      float a3 = (kk + 3 < K) ? Arow[kk + 3] : 0.f;
      av = make_float4(a0, a1, a2, a3);
      float b0 = (kk + 0 < K) ? Wrow[kk + 0] : 0.f;
      float b1 = (kk + 1 < K) ? Wrow[kk + 1] : 0.f;
      float b2 = (kk + 2 < K) ? Wrow[kk + 2] : 0.f;
      float b3 = (kk + 3 < K) ? Wrow[kk + 3] : 0.f;
      bv = make_float4(b0, b1, b2, b3);
    }
    As[lk + 0][lrow] = av.x; As[lk + 1][lrow] = av.y;
    As[lk + 2][lrow] = av.z; As[lk + 3][lrow] = av.w;
    Bs[lk + 0][lrow] = bv.x; Bs[lk + 1][lrow] = bv.y;
    Bs[lk + 2][lrow] = bv.z; Bs[lk + 3][lrow] = bv.w;
    __syncthreads();

    #pragma unroll
    for (int k = 0; k < BK; ++k) {
      float4 a4 = *(const float4*)&As[k][ty * 4];
      float4 b4 = *(const float4*)&Bs[k][tx * 4];
      float a[4] = {a4.x, a4.y, a4.z, a4.w};
      float bb[4] = {b4.x, b4.y, b4.z, b4.w};
      #pragma unroll
      for (int i = 0; i < 4; ++i)
        #pragma unroll
        for (int j = 0; j < 4; ++j)
          acc[i][j] += a[i] * bb[j];
    }
    __syncthreads();
  }

  #pragma unroll
  for (int i = 0; i < 4; ++i) {
    int r = row0 + ty * 4 + i;
    #pragma unroll
    for (int j = 0; j < 4; ++j) {
      int cidx = wcol0 + tx * 4 + j;
      C[(size_t)r * 1024 + col0 + tx * 4 + j] = acc[i][j] + bias[cidx];
    }
  }
}

// ---------------------------------------------------------------------------
// BiLSTM recurrence. One block per (sample, direction). 512 threads, thread j
// owns gate row j. U row = 128 floats pinned in VGPRs via empty-asm dataflow
// severing (round-1 named-float4 version still got sunk back into per-step
// cache re-fetch: VGPR=76, 3040 cyc/step, L2-BW bound).
// h is wave-uniform: cooperative ds_read_b64 (lane l holds h[2l..2l+1]) +
// v_readlane broadcast into SGPR operands of v_fmac.
// Gate order (PyTorch): i, f, g, o. gates layout: [b*L + t][1024], fwd|bwd.
// ---------------------------------------------------------------------------
__global__ __launch_bounds__(512, 1) void lstm_kernel(
    const float* __restrict__ gates,
    const float* __restrict__ Uf, const float* __restrict__ Ub,
    float* __restrict__ h_seq)
{
  int blk = blockIdx.x;      // 0..127
  int b = blk & 63;
  int dir = blk >> 6;
  int j = threadIdx.x;       // 0..511
  int lane = j & 63;

  const float* U = dir ? Ub : Uf;
  const float4* Urow = (const float4*)(U + (size_t)j * Hq);

  // Load U row into 128 named scalars and PIN them: the empty asm makes each
  // value an opaque function of the load, so the compiler cannot sink or
  // rematerialize the loads inside the time loop. ~180 VGPR < 256 cap.
#define ULOAD(m) \
  float4 uv##m = Urow[m]; \
  float u##m##x = uv##m.x, u##m##y = uv##m.y, u##m##z = uv##m.z, u##m##w = uv##m.w; \
  asm volatile("" : "+v"(u##m##x), "+v"(u##m##y), "+v"(u##m##z), "+v"(u##m##w));
  ULOAD(0)  ULOAD(1)  ULOAD(2)  ULOAD(3)  ULOAD(4)  ULOAD(5)  ULOAD(6)  ULOAD(7)
  ULOAD(8)  ULOAD(9)  ULOAD(10) ULOAD(11) ULOAD(12) ULOAD(13) ULOAD(14) ULOAD(15)
  ULOAD(16) ULOAD(17) ULOAD(18) ULOAD(19) ULOAD(20) ULOAD(21) ULOAD(22) ULOAD(23)
  ULOAD(24) ULOAD(25) ULOAD(26) ULOAD(27) ULOAD(28) ULOAD(29) ULOAD(30) ULOAD(31)
#undef ULOAD

  __shared__ float h_sh[Hq];
  __shared__ float nl_sh[512];
  if (j < Hq) h_sh[j] = 0.f;
  float c = 0.f;

  const float* gbase = gates + ((size_t)b * Lq) * 1024 + dir * 512 + j;
  int tt0 = dir ? (Lq - 1) : 0;
  float gcur = gbase[(size_t)tt0 * 1024];
  __syncthreads();

  int grp = j >> 7;   // 0:i 1:f 2:g 3:o (wave-uniform: 128-aligned groups)

  for (int t = 0; t < Lq; ++t) {
    // prefetch next step's gate row (hidden under this step's compute)
    float gnext = 0.f;
    int tn = t + 1;
    if (tn < Lq) {
      int ttn = dir ? (Lq - 1 - tn) : tn;
      gnext = gbase[(size_t)ttn * 1024];
    }

    // cooperative h fetch: lane l holds h[2l], h[2l+1]
    float2 hp = *(const float2*)(h_sh + lane * 2);
    int hx = __float_as_int(hp.x);
    int hy = __float_as_int(hp.y);

    float a0 = 0.f, a1 = 0.f, a2 = 0.f, a3 = 0.f;
#define ACC(m) { \
    a0 = fmaf(__int_as_float(__builtin_amdgcn_readlane(hx, 2*m)),     u##m##x, a0); \
    a1 = fmaf(__int_as_float(__builtin_amdgcn_readlane(hy, 2*m)),     u##m##y, a1); \
    a2 = fmaf(__int_as_float(__builtin_amdgcn_readlane(hx, 2*m + 1)), u##m##z, a2); \
    a3 = fmaf(__int_as_float(__builtin_amdgcn_readlane(hy, 2*m + 1)), u##m##w, a3); }
    ACC(0)  ACC(1)  ACC(2)  ACC(3)  ACC(4)  ACC(5)  ACC(6)  ACC(7)
    ACC(8)  ACC(9)  ACC(10) ACC(11) ACC(12) ACC(13) ACC(14) ACC(15)
    ACC(16) ACC(17) ACC(18) ACC(19) ACC(20) ACC(21) ACC(22) ACC(23)
    ACC(24) ACC(25) ACC(26) ACC(27) ACC(28) ACC(29) ACC(30) ACC(31)
#undef ACC

    float g = gcur + ((a0 + a2) + (a1 + a3));
    gcur = gnext;

    // per-gate nonlinearity on ALL 512 threads (wave-uniform branch)
    float nl = (grp == 2) ? tanhf(g) : 1.f / (1.f + __expf(-g));
    nl_sh[j] = nl;
    __syncthreads();

    if (j < Hq) {
      float si = nl_sh[j];
      float sf = nl_sh[j + 128];
      float tg = nl_sh[j + 256];
      float so = nl_sh[j + 384];
      c = sf * c + si * tg;
      float h = so * tanhf(c);
      h_sh[j] = h;
      int tt = dir ? (Lq - 1 - t) : t;
      h_seq[((size_t)b * Lq + tt) * 256 + dir * Hq + j] = h;
    }
    __syncthreads();
  }
}

// ---------------------------------------------------------------------------
// GAT1 attention-score projections: s_src/s_trg[b,l,h] from proj1 [M,64]
// ---------------------------------------------------------------------------
__global__ void srctrg_kernel(const float* __restrict__ proj1,
                              const float* __restrict__ a_src,
                              const float* __restrict__ a_trg,
                              float* __restrict__ s_src, float* __restrict__ s_trg)
{
  int m = blockIdx.x * blockDim.x + threadIdx.x;
  if (m >= MQ) return;
  const float* p = proj1 + (size_t)m * 64;
  #pragma unroll
  for (int h = 0; h < 8; ++h) {
    float ss = 0.f, st = 0.f;
    #pragma unroll
    for (int f = 0; f < 8; ++f) {
      float v = p[h * 8 + f];
      ss += v * a_src[h * 8 + f];
      st += v * a_trg[h * 8 + f];
    }
    s_src[(size_t)m * 8 + h] = ss;
    s_trg[(size_t)m * 8 + h] = st;
  }
}

// ---------------------------------------------------------------------------
// GAT1 per-graph max: m1[b] = lrelu( max_h ( max_s src[b,s,h] + max_t trg[b,t,h] ) )
// ---------------------------------------------------------------------------
__global__ __launch_bounds__(256) void gat1max_kernel(
    const float* __restrict__ s_src, const float* __restrict__ s_trg,
    float* __restrict__ m1)
{
  int b = blockIdx.x;
  int tid = threadIdx.x;
  int h = tid >> 5, r = tid & 31;
  float ms = -3.4e38f, mt = -3.4e38f;
  for (int s = r; s < Lq; s += 32) {
    ms = fmaxf(ms, s_src[((size_t)b * Lq + s) * 8 + h]);
    mt = fmaxf(mt, s_trg[((size_t)b * Lq + s) * 8 + h]);
  }
  #pragma unroll
  for (int o = 16; o > 0; o >>= 1) {
    ms = fmaxf(ms, __shfl_xor(ms, o, 32));
    mt = fmaxf(mt, __shfl_xor(mt, o, 32));
  }
  __shared__ float hh[8];
  if (r == 0) hh[h] = ms + mt;
  __syncthreads();
  if (tid == 0) {
    float mm = -3.4e38f;
    #pragma unroll
    for (int k = 0; k < 8; ++k) mm = fmaxf(mm, hh[k]);
    m1[b] = lrelu(mm);
  }
}

// ---------------------------------------------------------------------------
// GAT1 aggregation: block per (b,h); thread per target t.
// ---------------------------------------------------------------------------
__global__ __launch_bounds__(256) void gat1_agg_kernel(
    const float* __restrict__ s_src, const float* __restrict__ s_trg,
    const float* __restrict__ proj1, const float* __restrict__ m1,
    const float* __restrict__ g1_b, float* __restrict__ h1)
{
  int b = blockIdx.x >> 3;
  int h = blockIdx.x & 7;
  int t = threadIdx.x;
  __shared__ float src_s[Lq], trg_s[Lq];
  __shared__ float proj_s[Lq * 8];

  size_t base = (size_t)b * Lq;
  src_s[t] = s_src[(base + t) * 8 + h];
  trg_s[t] = s_trg[(base + t) * 8 + h];
  {
    const float4* pr = (const float4*)(proj1 + (base + t) * 64 + h * 8);
    float4* psh = (float4*)(proj_s + t * 8);
    psh[0] = pr[0];
    psh[1] = pr[1];
  }
  __syncthreads();

  float m = m1[b];
  float mytrg = trg_s[t];
  float den = 1e-16f;
  float acc[8] = {};
  for (int s = 0; s < Lq; ++s) {
    float w = __expf(lrelu(src_s[s] + mytrg) - m);
    den += w;
    const float* ps = proj_s + s * 8;
    #pragma unroll
    for (int f = 0; f < 8; ++f) acc[f] += w * ps[f];
  }
  float inv = 1.f / den;
  float* out = h1 + (base + t) * 64 + h * 8;
  #pragma unroll
  for (int f = 0; f < 8; ++f) {
    float v = acc[f] * inv + g1_b[h * 8 + f];
    out[f] = v > 0.f ? v : expm1f(v);   // ELU
  }
}

// ---------------------------------------------------------------------------
// block reductions over 256 threads (4 waves of 64)
// ---------------------------------------------------------------------------
__device__ __forceinline__ float block_max_256(float v, volatile float* red) {
  #pragma unroll
  for (int o = 32; o > 0; o >>= 1) v = fmaxf(v, __shfl_xor(v, o, 64));
  int tid = threadIdx.x;
  if ((tid & 63) == 0) red[tid >> 6] = v;
  __syncthreads();
  float r = fmaxf(fmaxf(red[0], red[1]), fmaxf(red[2], red[3]));
  __syncthreads();
  return r;
}
__device__ __forceinline__ float block_sum_256(float v, volatile float* red) {
  #pragma unroll
  for (int o = 32; o > 0; o >>= 1) v += __shfl_xor(v, o, 64);
  int tid = threadIdx.x;
  if ((tid & 63) == 0) red[tid >> 6] = v;
  __syncthreads();
  float r = red[0] + red[1] + red[2] + red[3];
  __syncthreads();
  return r;
}

// ---------------------------------------------------------------------------
// GAT2 (1 head, 1 feat) -> att weights -> softmax -> weighted-max pooling.
// ---------------------------------------------------------------------------
__global__ __launch_bounds__(256) void gat2_att_pool_kernel(
    const float* __restrict__ h1, const float* __restrict__ g2_W,
    const float* __restrict__ g2_src, const float* __restrict__ g2_trg,
    const float* __restrict__ ctx, const float* __restrict__ h_seq,
    float* __restrict__ att_out, float* __restrict__ pooled)
{
  int b = blockIdx.x;
  int tid = threadIdx.x;
  __shared__ float w2[64];
  __shared__ float src2[Lq], trg2[Lq], dq[Lq], att_sh[Lq];
  __shared__ float red[4];

  if (tid < 64) w2[tid] = g2_W[tid];
  __syncthreads();

  const float* hr = h1 + ((size_t)b * Lq + tid) * 64;
  float p = 0.f;
  #pragma unroll
  for (int k = 0; k < 64; ++k) p += hr[k] * w2[k];
  float a_s = g2_src[0], a_t = g2_trg[0];
  src2[tid] = p * a_s;
  trg2[tid] = p * a_t;
  __syncthreads();

  float ms = block_max_256(src2[tid], red);
  float mt = block_max_256(trg2[tid], red);
  float m2 = lrelu(ms + mt);

  float mytrg = trg2[tid];
  float den = 1e-16f;
  for (int s = 0; s < Lq; ++s)
    den += __expf(lrelu(src2[s] + mytrg) - m2);
  dq[tid] = ctx[tid] / den;
  __syncthreads();

  float mysrc = src2[tid];
  float raw = 0.f;
  for (int t = 0; t < Lq; ++t)
    raw += dq[t] * __expf(lrelu(mysrc + trg2[t]) - m2);

  float mr = block_max_256(raw, red);
  float e = __expf(raw - mr);
  float ssum = block_sum_256(e, red);
  float att = e / ssum;
  att_out[(size_t)b * Lq + tid] = att;
  att_sh[tid] = att;
  __syncthreads();

  float pm = -3.4e38f;
  for (int l = 0; l < Lq; ++l)
    pm = fmaxf(pm, h_seq[((size_t)b * Lq + l) * 256 + tid] * att_sh[l]);
  pooled[(size_t)b * 256 + tid] = pm;
}

// ---------------------------------------------------------------------------
// Head
// ---------------------------------------------------------------------------
__global__ __launch_bounds__(256) void head_kernel(
    const float* __restrict__ pooled, const float* __restrict__ lin_W,
    const float* __restrict__ lin_b, const float* __restrict__ out_W,
    const float* __restrict__ out_b, float* __restrict__ logits)
{
  __shared__ float hcl[64 * 64];
  int tid = threadIdx.x;
  for (int r = 0; r < 16; ++r) {
    int idx = r * 256 + tid;        // idx = i*64 + j
    int i = idx >> 6, j = idx & 63;
    const float* pr = pooled + i * 256;
    const float* wr = lin_W + j * 256;
    float d = lin_b[j];
    for (int k = 0; k < 256; ++k) d += pr[k] * wr[k];
    hcl[idx] = fmaxf(d, 0.f);
  }
  __syncthreads();
  if (tid < 128) {
    int i = tid >> 1, cc = tid & 1;
    const float* hr = hcl + i * 64;
    const float* wr = out_W + cc * 64;
    float d = out_b[cc];
    #pragma unroll
    for (int k = 0; k < 64; ++k) d += hr[k] * wr[k];
    logits[i * 2 + cc] = d;
  }
}

// ---------------------------------------------------------------------------
extern "C" void kernel_launch(void* const* d_in, const int* in_sizes, int n_in,
                              void* d_out, int out_size, void* d_ws, size_t ws_size,
                              hipStream_t stream)
{
  const int*   ids    = (const int*)  d_in[0];
  // d_in[1] = attention_mask (all ones by construction; unused)
  const float* emb    = (const float*)d_in[2];
  const float* Wih_f  = (const float*)d_in[3];
  const float* Whh_f  = (const float*)d_in[4];
  const float* b_f    = (const float*)d_in[5];
  const float* Wih_b  = (const float*)d_in[6];
  const float* Whh_b  = (const float*)d_in[7];
  const float* b_b    = (const float*)d_in[8];
  const float* g1_W   = (const float*)d_in[9];
  const float* g1_src = (const float*)d_in[10];
  const float* g1_trg = (const float*)d_in[11];
  const float* g1_b   = (const float*)d_in[12];
  const float* g2_W   = (const float*)d_in[13];
  const float* g2_src = (const float*)d_in[14];
  const float* g2_trg = (const float*)d_in[15];
  // d_in[16] = g2_b (unused)
  const float* ctx    = (const float*)d_in[17];
  const float* lin_W  = (const float*)d_in[18];
  const float* lin_b  = (const float*)d_in[19];
  const float* out_W  = (const float*)d_in[20];
  const float* out_b  = (const float*)d_in[21];

  float* out_f   = (float*)d_out;
  float* logits  = out_f;          // [64,2]
  float* att_out = out_f + 128;    // [64,256]

  float* ws = (float*)d_ws;
  const size_t M = MQ;
  float* gates   = ws; ws += M * 1024;   // [M][1024] fwd|bwd
  float* h_seq   = ws; ws += M * 256;
  float* proj1   = ws; ws += M * 64;
  float* s_src   = ws; ws += M * 8;
  float* s_trg   = ws; ws += M * 8;
  float* h1      = ws; ws += M * 64;
  float* m1      = ws; ws += 64;
  float* pooled  = ws; ws += 64 * 256;

  dim3 thr(256);

  // Stage A: fused embedding-gather + both input-gate GEMMs (K=300, N=1024)
  gemm_gates<<<dim3(MQ / BM, 1024 / BN), thr, 0, stream>>>(emb, ids, Wih_f, b_f, Wih_b, b_b, gates);

  // Stage B: BiLSTM recurrence
  lstm_kernel<<<128, 512, 0, stream>>>(gates, Whh_f, Whh_b, h_seq);

  // Stage C: GAT layer 1
  gemm_awt<<<dim3(MQ / BM, 1), thr, 0, stream>>>(h_seq, nullptr, g1_W, nullptr, proj1, MQ, 64, 256);
  srctrg_kernel<<<MQ / 256, thr, 0, stream>>>(proj1, g1_src, g1_trg, s_src, s_trg);
  gat1max_kernel<<<Bq, thr, 0, stream>>>(s_src, s_trg, m1);
  gat1_agg_kernel<<<Bq * 8, thr, 0, stream>>>(s_src, s_trg, proj1, m1, g1_b, h1);

  // Stage D: GAT layer 2 attention -> context attention -> softmax -> pooling
  gat2_att_pool_kernel<<<Bq, thr, 0, stream>>>(h1, g2_W, g2_src, g2_trg, ctx, h_seq, att_out, pooled);

  // Stage E: classifier head
  head_kernel<<<1, thr, 0, stream>>>(pooled, lin_W, lin_b, out_W, out_b, logits);
}

// Round 4
// 681.309 us; speedup vs baseline: 1.0333x; 1.0333x over previous
//
#include <hip/hip_runtime.h>
#include <math.h>

#define Bq 64
#define Lq 256
#define Eq 300
#define Hq 128
#define MQ (Bq*Lq)   // 16384

#define LRELU_S 0.2f

__device__ __forceinline__ float lrelu(float x) { return x > 0.f ? x : LRELU_S * x; }

// call-free tanh: one v_exp + div, exact sign/saturation behavior
__device__ __forceinline__ float tanh_fast(float x) {
  float ax = fabsf(x);
  float e = __expf(-2.f * ax);          // (0,1], never overflows
  float r = (1.f - e) / (1.f + e);
  return copysignf(r, x);
}

// ---------------------------------------------------------------------------
// Generic tiled GEMM: C[m,n] = sum_k A[m,k]*W[n,k] (+ bias[n])
// ---------------------------------------------------------------------------
#define BM 64
#define BN 64
#define BK 16

__global__ __launch_bounds__(256) void gemm_awt(
    const float* __restrict__ Asrc, const int* __restrict__ ids,
    const float* __restrict__ W, const float* __restrict__ bias,
    float* __restrict__ C, int M, int N, int K)
{
  __shared__ float As[BK][BM + 4];
  __shared__ float Bs[BK][BN + 4];
  int tid = threadIdx.x;
  int tx = tid & 15, ty = tid >> 4;
  int row0 = blockIdx.x * BM, col0 = blockIdx.y * BN;

  int lrow = tid >> 2;          // 0..63
  int lk   = (tid & 3) << 2;    // 0,4,8,12

  const float* Arow;
  {
    int r = row0 + lrow;
    int id = ids ? ids[r] : r;
    Arow = Asrc + (size_t)id * K;
  }
  const float* Wrow = W + (size_t)(col0 + lrow) * K;

  float acc[4][4] = {};

  for (int k0 = 0; k0 < K; k0 += BK) {
    int kk = k0 + lk;
    float4 av, bv;
    if (kk + 3 < K) {
      av = *(const float4*)(Arow + kk);
      bv = *(const float4*)(Wrow + kk);
    } else {
      float a0 = (kk + 0 < K) ? Arow[kk + 0] : 0.f;
      float a1 = (kk + 1 < K) ? Arow[kk + 1] : 0.f;
      float a2 = (kk + 2 < K) ? Arow[kk + 2] : 0.f;
      float a3 = (kk + 3 < K) ? Arow[kk + 3] : 0.f;
      av = make_float4(a0, a1, a2, a3);
      float b0 = (kk + 0 < K) ? Wrow[kk + 0] : 0.f;
      float b1 = (kk + 1 < K) ? Wrow[kk + 1] : 0.f;
      float b2 = (kk + 2 < K) ? Wrow[kk + 2] : 0.f;
      float b3 = (kk + 3 < K) ? Wrow[kk + 3] : 0.f;
      bv = make_float4(b0, b1, b2, b3);
    }
    As[lk + 0][lrow] = av.x; As[lk + 1][lrow] = av.y;
    As[lk + 2][lrow] = av.z; As[lk + 3][lrow] = av.w;
    Bs[lk + 0][lrow] = bv.x; Bs[lk + 1][lrow] = bv.y;
    Bs[lk + 2][lrow] = bv.z; Bs[lk + 3][lrow] = bv.w;
    __syncthreads();

    #pragma unroll
    for (int k = 0; k < BK; ++k) {
      float4 a4 = *(const float4*)&As[k][ty * 4];
      float4 b4 = *(const float4*)&Bs[k][tx * 4];
      float a[4] = {a4.x, a4.y, a4.z, a4.w};
      float bb[4] = {b4.x, b4.y, b4.z, b4.w};
      #pragma unroll
      for (int i = 0; i < 4; ++i)
        #pragma unroll
        for (int j = 0; j < 4; ++j)
          acc[i][j] += a[i] * bb[j];
    }
    __syncthreads();
  }

  #pragma unroll
  for (int i = 0; i < 4; ++i) {
    int r = row0 + ty * 4 + i;
    #pragma unroll
    for (int j = 0; j < 4; ++j) {
      int cidx = col0 + tx * 4 + j;
      float v = acc[i][j] + (bias ? bias[cidx] : 0.f);
      C[(size_t)r * N + cidx] = v;
    }
  }
}

// ---------------------------------------------------------------------------
// Fused gates GEMM, 128x128 tile: C[m, 0:512] = emb[ids[m]] @ Wih_f^T + b_f
//                                 C[m, 512:1024] = emb[ids[m]] @ Wih_b^T + b_b
// 2x2 blocks of 4x4 acc per thread; float4 LDS reads at stride 4 within each
// 64-col half -> <=2-way bank aliasing (free).
// ---------------------------------------------------------------------------
#define GBM 128
#define GBN 128
#define GBK 16

__global__ __launch_bounds__(256) void gemm_gates(
    const float* __restrict__ emb, const int* __restrict__ ids,
    const float* __restrict__ Wf, const float* __restrict__ bf,
    const float* __restrict__ Wb, const float* __restrict__ bb_,
    float* __restrict__ C)
{
  const int K = Eq;  // 300
  __shared__ float As[GBK][GBM + 4];
  __shared__ float Bs[GBK][GBN + 4];
  int tid = threadIdx.x;
  int tx = tid & 15, ty = tid >> 4;
  int row0 = blockIdx.x * GBM;
  int col0 = blockIdx.y * GBN;          // 0..896; 128 | 512 so one half per block
  const float* W    = (col0 < 512) ? Wf : Wb;
  const float* bias = (col0 < 512) ? bf : bb_;
  int wcol0 = col0 & 511;

  int lrow = tid >> 1;          // 0..127
  int lk8  = (tid & 1) << 3;    // 0 or 8

  const float* Arow = emb + (size_t)ids[row0 + lrow] * K;
  const float* Wrow = W + (size_t)(wcol0 + lrow) * K;

  float acc[2][2][4][4] = {};

  for (int k0 = 0; k0 < K; k0 += GBK) {
    #pragma unroll
    for (int half = 0; half < 2; ++half) {
      int kk = k0 + lk8 + half * 4;
      float4 av, bv;
      if (kk + 3 < K) {
        av = *(const float4*)(Arow + kk);
        bv = *(const float4*)(Wrow + kk);
      } else {
        float aa[4], bw[4];
        #pragma unroll
        for (int q = 0; q < 4; ++q) {
          aa[q] = (kk + q < K) ? Arow[kk + q] : 0.f;
          bw[q] = (kk + q < K) ? Wrow[kk + q] : 0.f;
        }
        av = make_float4(aa[0], aa[1], aa[2], aa[3]);
        bv = make_float4(bw[0], bw[1], bw[2], bw[3]);
      }
      int kb = lk8 + half * 4;
      As[kb + 0][lrow] = av.x; As[kb + 1][lrow] = av.y;
      As[kb + 2][lrow] = av.z; As[kb + 3][lrow] = av.w;
      Bs[kb + 0][lrow] = bv.x; Bs[kb + 1][lrow] = bv.y;
      Bs[kb + 2][lrow] = bv.z; Bs[kb + 3][lrow] = bv.w;
    }
    __syncthreads();

    #pragma unroll
    for (int k = 0; k < GBK; ++k) {
      float4 a0 = *(const float4*)&As[k][ty * 4];
      float4 a1 = *(const float4*)&As[k][64 + ty * 4];
      float4 b0 = *(const float4*)&Bs[k][tx * 4];
      float4 b1 = *(const float4*)&Bs[k][64 + tx * 4];
      float av_[2][4] = {{a0.x, a0.y, a0.z, a0.w}, {a1.x, a1.y, a1.z, a1.w}};
      float bv_[2][4] = {{b0.x, b0.y, b0.z, b0.w}, {b1.x, b1.y, b1.z, b1.w}};
      #pragma unroll
      for (int ra = 0; ra < 2; ++ra)
        #pragma unroll
        for (int rb = 0; rb < 2; ++rb)
          #pragma unroll
          for (int i = 0; i < 4; ++i)
            #pragma unroll
            for (int j = 0; j < 4; ++j)
              acc[ra][rb][i][j] += av_[ra][i] * bv_[rb][j];
    }
    __syncthreads();
  }

  #pragma unroll
  for (int ra = 0; ra < 2; ++ra)
    #pragma unroll
    for (int i = 0; i < 4; ++i) {
      int r = row0 + ra * 64 + ty * 4 + i;
      #pragma unroll
      for (int rb = 0; rb < 2; ++rb)
        #pragma unroll
        for (int j = 0; j < 4; ++j) {
          int cc = rb * 64 + tx * 4 + j;
          C[(size_t)r * 1024 + col0 + cc] = acc[ra][rb][i][j] + bias[wcol0 + cc];
        }
    }
}

// ---------------------------------------------------------------------------
// BiLSTM recurrence. One block per (sample, direction), 512 threads.
// Row mapping puts the 4 gates of h-index hidx in lanes {l, l+16, l+32, l+48}
// of ONE wave: wave w, lane l -> gate = l>>4, hidx = 16w + (l&15),
// row = gate*128 + hidx. Gate exchange is 4 __shfl (no LDS, no barrier).
// U row (128 floats) pinned in VGPRs via empty asm; loop body is CALL-FREE
// (tanh/sigmoid via __expf) so the allocator has no call-clobber pressure —
// rounds 1-2 spilled U because tanhf() lowered to an OCML call (VGPR=76).
// h double-buffered in LDS -> single barrier per step.
// ---------------------------------------------------------------------------
__global__ __launch_bounds__(512, 1) void lstm_kernel(
    const float* __restrict__ gates,
    const float* __restrict__ Uf, const float* __restrict__ Ub,
    float* __restrict__ h_seq)
{
  int blk = blockIdx.x;      // 0..127
  int b = blk & 63;
  int dir = blk >> 6;
  int j = threadIdx.x;       // 0..511
  int lane = j & 63;
  int w = j >> 6;            // wave 0..7
  int gate = (lane >> 4) & 3;          // 0:i 1:f 2:g 3:o
  int hidx = (w << 4) | (lane & 15);   // 0..127
  int row = (gate << 7) | hidx;        // 0..511

  const float* U = dir ? Ub : Uf;
  const float4* Urow = (const float4*)(U + (size_t)row * Hq);

#define ULOAD(m) \
  float4 uv##m = Urow[m]; \
  float u##m##x = uv##m.x, u##m##y = uv##m.y, u##m##z = uv##m.z, u##m##w = uv##m.w; \
  asm volatile("" : "+v"(u##m##x), "+v"(u##m##y), "+v"(u##m##z), "+v"(u##m##w));
  ULOAD(0)  ULOAD(1)  ULOAD(2)  ULOAD(3)  ULOAD(4)  ULOAD(5)  ULOAD(6)  ULOAD(7)
  ULOAD(8)  ULOAD(9)  ULOAD(10) ULOAD(11) ULOAD(12) ULOAD(13) ULOAD(14) ULOAD(15)
  ULOAD(16) ULOAD(17) ULOAD(18) ULOAD(19) ULOAD(20) ULOAD(21) ULOAD(22) ULOAD(23)
  ULOAD(24) ULOAD(25) ULOAD(26) ULOAD(27) ULOAD(28) ULOAD(29) ULOAD(30) ULOAD(31)
#undef ULOAD

  __shared__ __align__(16) float h_sh[2][Hq];
  if (j < Hq) h_sh[0][j] = 0.f;
  float c = 0.f;

  const float* gbase = gates + ((size_t)b * Lq) * 1024 + dir * 512 + row;
  int tt0 = dir ? (Lq - 1) : 0;
  float gcur = gbase[(size_t)tt0 * 1024];
  __syncthreads();

  for (int t = 0; t < Lq; ++t) {
    // prefetch next step's gate value (latency hidden under the fma chain)
    float gnext = 0.f;
    int tn = t + 1;
    if (tn < Lq) {
      int ttn = dir ? (Lq - 1 - tn) : tn;
      gnext = gbase[(size_t)ttn * 1024];
    }

    // cooperative h fetch from current buffer: lane m holds h[2m], h[2m+1]
    float2 hp = *(const float2*)(&h_sh[t & 1][lane * 2]);
    int hx = __float_as_int(hp.x);
    int hy = __float_as_int(hp.y);

    float a0 = 0.f, a1 = 0.f, a2 = 0.f, a3 = 0.f;
#define ACC(m) { \
    a0 = fmaf(__int_as_float(__builtin_amdgcn_readlane(hx, 2*m)),     u##m##x, a0); \
    a1 = fmaf(__int_as_float(__builtin_amdgcn_readlane(hy, 2*m)),     u##m##y, a1); \
    a2 = fmaf(__int_as_float(__builtin_amdgcn_readlane(hx, 2*m + 1)), u##m##z, a2); \
    a3 = fmaf(__int_as_float(__builtin_amdgcn_readlane(hy, 2*m + 1)), u##m##w, a3); }
    ACC(0)  ACC(1)  ACC(2)  ACC(3)  ACC(4)  ACC(5)  ACC(6)  ACC(7)
    ACC(8)  ACC(9)  ACC(10) ACC(11) ACC(12) ACC(13) ACC(14) ACC(15)
    ACC(16) ACC(17) ACC(18) ACC(19) ACC(20) ACC(21) ACC(22) ACC(23)
    ACC(24) ACC(25) ACC(26) ACC(27) ACC(28) ACC(29) ACC(30) ACC(31)
#undef ACC

    float g = gcur + ((a0 + a2) + (a1 + a3));
    gcur = gnext;

    // branch-free nonlinearity: sigmoid for i/f/o, tanh for g. One v_exp each.
    bool isg = (gate == 2);
    float ax = fabsf(g);
    float arg = isg ? (-2.f * ax) : (-g);
    float e = __expf(arg);
    float inv = 1.f / (1.f + e);
    float r = isg ? (1.f - e) * inv : inv;
    float nl = isg ? copysignf(r, g) : r;

    // in-wave gate exchange: lanes {base, base+16, base+32, base+48} hold
    // i,f,g,o for the same hidx
    int base = lane & 15;
    float si = __shfl(nl, base,      64);
    float sf = __shfl(nl, base + 16, 64);
    float tg = __shfl(nl, base + 32, 64);
    float so = __shfl(nl, base + 48, 64);
    c = sf * c + si * tg;             // redundant across the 4 gate groups
    float h = so * tanh_fast(c);

    if (lane < 16) {
      h_sh[(t & 1) ^ 1][hidx] = h;
      int tt = dir ? (Lq - 1 - t) : t;
      h_seq[((size_t)b * Lq + tt) * 256 + dir * Hq + hidx] = h;
    }
    __syncthreads();
  }
}

// ---------------------------------------------------------------------------
// GAT1 attention-score projections: s_src/s_trg[b,l,h] from proj1 [M,64]
// ---------------------------------------------------------------------------
__global__ void srctrg_kernel(const float* __restrict__ proj1,
                              const float* __restrict__ a_src,
                              const float* __restrict__ a_trg,
                              float* __restrict__ s_src, float* __restrict__ s_trg)
{
  int m = blockIdx.x * blockDim.x + threadIdx.x;
  if (m >= MQ) return;
  const float* p = proj1 + (size_t)m * 64;
  #pragma unroll
  for (int h = 0; h < 8; ++h) {
    float ss = 0.f, st = 0.f;
    #pragma unroll
    for (int f = 0; f < 8; ++f) {
      float v = p[h * 8 + f];
      ss += v * a_src[h * 8 + f];
      st += v * a_trg[h * 8 + f];
    }
    s_src[(size_t)m * 8 + h] = ss;
    s_trg[(size_t)m * 8 + h] = st;
  }
}

// ---------------------------------------------------------------------------
// GAT1 per-graph max: m1[b] = lrelu( max_h ( max_s src + max_t trg ) )
// ---------------------------------------------------------------------------
__global__ __launch_bounds__(256) void gat1max_kernel(
    const float* __restrict__ s_src, const float* __restrict__ s_trg,
    float* __restrict__ m1)
{
  int b = blockIdx.x;
  int tid = threadIdx.x;
  int h = tid >> 5, r = tid & 31;
  float ms = -3.4e38f, mt = -3.4e38f;
  for (int s = r; s < Lq; s += 32) {
    ms = fmaxf(ms, s_src[((size_t)b * Lq + s) * 8 + h]);
    mt = fmaxf(mt, s_trg[((size_t)b * Lq + s) * 8 + h]);
  }
  #pragma unroll
  for (int o = 16; o > 0; o >>= 1) {
    ms = fmaxf(ms, __shfl_xor(ms, o, 32));
    mt = fmaxf(mt, __shfl_xor(mt, o, 32));
  }
  __shared__ float hh[8];
  if (r == 0) hh[h] = ms + mt;
  __syncthreads();
  if (tid == 0) {
    float mm = -3.4e38f;
    #pragma unroll
    for (int k = 0; k < 8; ++k) mm = fmaxf(mm, hh[k]);
    m1[b] = lrelu(mm);
  }
}

// ---------------------------------------------------------------------------
// GAT1 aggregation: block per (b,h); thread per target t.
// ---------------------------------------------------------------------------
__global__ __launch_bounds__(256) void gat1_agg_kernel(
    const float* __restrict__ s_src, const float* __restrict__ s_trg,
    const float* __restrict__ proj1, const float* __restrict__ m1,
    const float* __restrict__ g1_b, float* __restrict__ h1)
{
  int b = blockIdx.x >> 3;
  int h = blockIdx.x & 7;
  int t = threadIdx.x;
  __shared__ float src_s[Lq], trg_s[Lq];
  __shared__ float proj_s[Lq * 8];

  size_t base = (size_t)b * Lq;
  src_s[t] = s_src[(base + t) * 8 + h];
  trg_s[t] = s_trg[(base + t) * 8 + h];
  {
    const float4* pr = (const float4*)(proj1 + (base + t) * 64 + h * 8);
    float4* psh = (float4*)(proj_s + t * 8);
    psh[0] = pr[0];
    psh[1] = pr[1];
  }
  __syncthreads();

  float m = m1[b];
  float mytrg = trg_s[t];
  float den = 1e-16f;
  float acc[8] = {};
  for (int s = 0; s < Lq; ++s) {
    float w = __expf(lrelu(src_s[s] + mytrg) - m);
    den += w;
    const float* ps = proj_s + s * 8;
    #pragma unroll
    for (int f = 0; f < 8; ++f) acc[f] += w * ps[f];
  }
  float inv = 1.f / den;
  float* out = h1 + (base + t) * 64 + h * 8;
  #pragma unroll
  for (int f = 0; f < 8; ++f) {
    float v = acc[f] * inv + g1_b[h * 8 + f];
    out[f] = v > 0.f ? v : expm1f(v);   // ELU
  }
}

// ---------------------------------------------------------------------------
// block reductions over 256 threads (4 waves of 64)
// ---------------------------------------------------------------------------
__device__ __forceinline__ float block_max_256(float v, volatile float* red) {
  #pragma unroll
  for (int o = 32; o > 0; o >>= 1) v = fmaxf(v, __shfl_xor(v, o, 64));
  int tid = threadIdx.x;
  if ((tid & 63) == 0) red[tid >> 6] = v;
  __syncthreads();
  float r = fmaxf(fmaxf(red[0], red[1]), fmaxf(red[2], red[3]));
  __syncthreads();
  return r;
}
__device__ __forceinline__ float block_sum_256(float v, volatile float* red) {
  #pragma unroll
  for (int o = 32; o > 0; o >>= 1) v += __shfl_xor(v, o, 64);
  int tid = threadIdx.x;
  if ((tid & 63) == 0) red[tid >> 6] = v;
  __syncthreads();
  float r = red[0] + red[1] + red[2] + red[3];
  __syncthreads();
  return r;
}

// ---------------------------------------------------------------------------
// GAT2 (1 head, 1 feat) -> att weights -> softmax -> weighted-max pooling.
// ---------------------------------------------------------------------------
__global__ __launch_bounds__(256) void gat2_att_pool_kernel(
    const float* __restrict__ h1, const float* __restrict__ g2_W,
    const float* __restrict__ g2_src, const float* __restrict__ g2_trg,
    const float* __restrict__ ctx, const float* __restrict__ h_seq,
    float* __restrict__ att_out, float* __restrict__ pooled)
{
  int b = blockIdx.x;
  int tid = threadIdx.x;
  __shared__ float w2[64];
  __shared__ float src2[Lq], trg2[Lq], dq[Lq], att_sh[Lq];
  __shared__ float red[4];

  if (tid < 64) w2[tid] = g2_W[tid];
  __syncthreads();

  const float* hr = h1 + ((size_t)b * Lq + tid) * 64;
  float p = 0.f;
  #pragma unroll
  for (int k = 0; k < 64; ++k) p += hr[k] * w2[k];
  float a_s = g2_src[0], a_t = g2_trg[0];
  src2[tid] = p * a_s;
  trg2[tid] = p * a_t;
  __syncthreads();

  float ms = block_max_256(src2[tid], red);
  float mt = block_max_256(trg2[tid], red);
  float m2 = lrelu(ms + mt);

  float mytrg = trg2[tid];
  float den = 1e-16f;
  for (int s = 0; s < Lq; ++s)
    den += __expf(lrelu(src2[s] + mytrg) - m2);
  dq[tid] = ctx[tid] / den;
  __syncthreads();

  float mysrc = src2[tid];
  float raw = 0.f;
  for (int t = 0; t < Lq; ++t)
    raw += dq[t] * __expf(lrelu(mysrc + trg2[t]) - m2);

  float mr = block_max_256(raw, red);
  float e = __expf(raw - mr);
  float ssum = block_sum_256(e, red);
  float att = e / ssum;
  att_out[(size_t)b * Lq + tid] = att;
  att_sh[tid] = att;
  __syncthreads();

  float pm = -3.4e38f;
  for (int l = 0; l < Lq; ++l)
    pm = fmaxf(pm, h_seq[((size_t)b * Lq + l) * 256 + tid] * att_sh[l]);
  pooled[(size_t)b * 256 + tid] = pm;
}

// ---------------------------------------------------------------------------
// Head
// ---------------------------------------------------------------------------
__global__ __launch_bounds__(256) void head_kernel(
    const float* __restrict__ pooled, const float* __restrict__ lin_W,
    const float* __restrict__ lin_b, const float* __restrict__ out_W,
    const float* __restrict__ out_b, float* __restrict__ logits)
{
  __shared__ float hcl[64 * 64];
  int tid = threadIdx.x;
  for (int r = 0; r < 16; ++r) {
    int idx = r * 256 + tid;        // idx = i*64 + j
    int i = idx >> 6, j = idx & 63;
    const float* pr = pooled + i * 256;
    const float* wr = lin_W + j * 256;
    float d = lin_b[j];
    for (int k = 0; k < 256; ++k) d += pr[k] * wr[k];
    hcl[idx] = fmaxf(d, 0.f);
  }
  __syncthreads();
  if (tid < 128) {
    int i = tid >> 1, cc = tid & 1;
    const float* hr = hcl + i * 64;
    const float* wr = out_W + cc * 64;
    float d = out_b[cc];
    #pragma unroll
    for (int k = 0; k < 64; ++k) d += hr[k] * wr[k];
    logits[i * 2 + cc] = d;
  }
}

// ---------------------------------------------------------------------------
extern "C" void kernel_launch(void* const* d_in, const int* in_sizes, int n_in,
                              void* d_out, int out_size, void* d_ws, size_t ws_size,
                              hipStream_t stream)
{
  const int*   ids    = (const int*)  d_in[0];
  // d_in[1] = attention_mask (all ones by construction; unused)
  const float* emb    = (const float*)d_in[2];
  const float* Wih_f  = (const float*)d_in[3];
  const float* Whh_f  = (const float*)d_in[4];
  const float* b_f    = (const float*)d_in[5];
  const float* Wih_b  = (const float*)d_in[6];
  const float* Whh_b  = (const float*)d_in[7];
  const float* b_b    = (const float*)d_in[8];
  const float* g1_W   = (const float*)d_in[9];
  const float* g1_src = (const float*)d_in[10];
  const float* g1_trg = (const float*)d_in[11];
  const float* g1_b   = (const float*)d_in[12];
  const float* g2_W   = (const float*)d_in[13];
  const float* g2_src = (const float*)d_in[14];
  const float* g2_trg = (const float*)d_in[15];
  // d_in[16] = g2_b (unused)
  const float* ctx    = (const float*)d_in[17];
  const float* lin_W  = (const float*)d_in[18];
  const float* lin_b  = (const float*)d_in[19];
  const float* out_W  = (const float*)d_in[20];
  const float* out_b  = (const float*)d_in[21];

  float* out_f   = (float*)d_out;
  float* logits  = out_f;          // [64,2]
  float* att_out = out_f + 128;    // [64,256]

  float* ws = (float*)d_ws;
  const size_t M = MQ;
  float* gates   = ws; ws += M * 1024;   // [M][1024] fwd|bwd
  float* h_seq   = ws; ws += M * 256;
  float* proj1   = ws; ws += M * 64;
  float* s_src   = ws; ws += M * 8;
  float* s_trg   = ws; ws += M * 8;
  float* h1      = ws; ws += M * 64;
  float* m1      = ws; ws += 64;
  float* pooled  = ws; ws += 64 * 256;

  dim3 thr(256);

  // Stage A: fused embedding-gather + both input-gate GEMMs (K=300, N=1024)
  gemm_gates<<<dim3(MQ / GBM, 1024 / GBN), thr, 0, stream>>>(emb, ids, Wih_f, b_f, Wih_b, b_b, gates);

  // Stage B: BiLSTM recurrence
  lstm_kernel<<<128, 512, 0, stream>>>(gates, Whh_f, Whh_b, h_seq);

  // Stage C: GAT layer 1
  gemm_awt<<<dim3(MQ / BM, 1), thr, 0, stream>>>(h_seq, nullptr, g1_W, nullptr, proj1, MQ, 64, 256);
  srctrg_kernel<<<MQ / 256, thr, 0, stream>>>(proj1, g1_src, g1_trg, s_src, s_trg);
  gat1max_kernel<<<Bq, thr, 0, stream>>>(s_src, s_trg, m1);
  gat1_agg_kernel<<<Bq * 8, thr, 0, stream>>>(s_src, s_trg, proj1, m1, g1_b, h1);

  // Stage D: GAT layer 2 attention -> context attention -> softmax -> pooling
  gat2_att_pool_kernel<<<Bq, thr, 0, stream>>>(h1, g2_W, g2_src, g2_trg, ctx, h_seq, att_out, pooled);

  // Stage E: classifier head
  head_kernel<<<1, thr, 0, stream>>>(pooled, lin_W, lin_b, out_W, out_b, logits);
}

// Round 5
// 598.153 us; speedup vs baseline: 1.1769x; 1.1390x over previous
//
#include <hip/hip_runtime.h>
#include <math.h>

#define Bq 64
#define Lq 256
#define Eq 300
#define Hq 128
#define MQ (Bq*Lq)   // 16384

#define LRELU_S 0.2f

__device__ __forceinline__ float lrelu(float x) { return x > 0.f ? x : LRELU_S * x; }

// call-free tanh: one v_exp + div, exact sign/saturation behavior
__device__ __forceinline__ float tanh_fast(float x) {
  float ax = fabsf(x);
  float e = __expf(-2.f * ax);          // (0,1], never overflows
  float r = (1.f - e) / (1.f + e);
  return copysignf(r, x);
}

// ---------------------------------------------------------------------------
// Generic tiled GEMM: C[m,n] = sum_k A[m,k]*W[n,k] (+ bias[n])
// ---------------------------------------------------------------------------
#define BM 64
#define BN 64
#define BK 16

__global__ __launch_bounds__(256) void gemm_awt(
    const float* __restrict__ Asrc, const int* __restrict__ ids,
    const float* __restrict__ W, const float* __restrict__ bias,
    float* __restrict__ C, int M, int N, int K)
{
  __shared__ float As[BK][BM + 4];
  __shared__ float Bs[BK][BN + 4];
  int tid = threadIdx.x;
  int tx = tid & 15, ty = tid >> 4;
  int row0 = blockIdx.x * BM, col0 = blockIdx.y * BN;

  int lrow = tid >> 2;          // 0..63
  int lk   = (tid & 3) << 2;    // 0,4,8,12

  const float* Arow;
  {
    int r = row0 + lrow;
    int id = ids ? ids[r] : r;
    Arow = Asrc + (size_t)id * K;
  }
  const float* Wrow = W + (size_t)(col0 + lrow) * K;

  float acc[4][4] = {};

  for (int k0 = 0; k0 < K; k0 += BK) {
    int kk = k0 + lk;
    float4 av, bv;
    if (kk + 3 < K) {
      av = *(const float4*)(Arow + kk);
      bv = *(const float4*)(Wrow + kk);
    } else {
      float a0 = (kk + 0 < K) ? Arow[kk + 0] : 0.f;
      float a1 = (kk + 1 < K) ? Arow[kk + 1] : 0.f;
      float a2 = (kk + 2 < K) ? Arow[kk + 2] : 0.f;
      float a3 = (kk + 3 < K) ? Arow[kk + 3] : 0.f;
      av = make_float4(a0, a1, a2, a3);
      float b0 = (kk + 0 < K) ? Wrow[kk + 0] : 0.f;
      float b1 = (kk + 1 < K) ? Wrow[kk + 1] : 0.f;
      float b2 = (kk + 2 < K) ? Wrow[kk + 2] : 0.f;
      float b3 = (kk + 3 < K) ? Wrow[kk + 3] : 0.f;
      bv = make_float4(b0, b1, b2, b3);
    }
    As[lk + 0][lrow] = av.x; As[lk + 1][lrow] = av.y;
    As[lk + 2][lrow] = av.z; As[lk + 3][lrow] = av.w;
    Bs[lk + 0][lrow] = bv.x; Bs[lk + 1][lrow] = bv.y;
    Bs[lk + 2][lrow] = bv.z; Bs[lk + 3][lrow] = bv.w;
    __syncthreads();

    #pragma unroll
    for (int k = 0; k < BK; ++k) {
      float4 a4 = *(const float4*)&As[k][ty * 4];
      float4 b4 = *(const float4*)&Bs[k][tx * 4];
      float a[4] = {a4.x, a4.y, a4.z, a4.w};
      float bb[4] = {b4.x, b4.y, b4.z, b4.w};
      #pragma unroll
      for (int i = 0; i < 4; ++i)
        #pragma unroll
        for (int j = 0; j < 4; ++j)
          acc[i][j] += a[i] * bb[j];
    }
    __syncthreads();
  }

  #pragma unroll
  for (int i = 0; i < 4; ++i) {
    int r = row0 + ty * 4 + i;
    #pragma unroll
    for (int j = 0; j < 4; ++j) {
      int cidx = col0 + tx * 4 + j;
      float v = acc[i][j] + (bias ? bias[cidx] : 0.f);
      C[(size_t)r * N + cidx] = v;
    }
  }
}

// ---------------------------------------------------------------------------
// Fused gates GEMM, 128x128 tile: C[m, 0:512] = emb[ids[m]] @ Wih_f^T + b_f
//                                 C[m, 512:1024] = emb[ids[m]] @ Wih_b^T + b_b
// ---------------------------------------------------------------------------
#define GBM 128
#define GBN 128
#define GBK 16

__global__ __launch_bounds__(256) void gemm_gates(
    const float* __restrict__ emb, const int* __restrict__ ids,
    const float* __restrict__ Wf, const float* __restrict__ bf,
    const float* __restrict__ Wb, const float* __restrict__ bb_,
    float* __restrict__ C)
{
  const int K = Eq;  // 300
  __shared__ float As[GBK][GBM + 4];
  __shared__ float Bs[GBK][GBN + 4];
  int tid = threadIdx.x;
  int tx = tid & 15, ty = tid >> 4;
  int row0 = blockIdx.x * GBM;
  int col0 = blockIdx.y * GBN;          // 0..896; 128 | 512 so one half per block
  const float* W    = (col0 < 512) ? Wf : Wb;
  const float* bias = (col0 < 512) ? bf : bb_;
  int wcol0 = col0 & 511;

  int lrow = tid >> 1;          // 0..127
  int lk8  = (tid & 1) << 3;    // 0 or 8

  const float* Arow = emb + (size_t)ids[row0 + lrow] * K;
  const float* Wrow = W + (size_t)(wcol0 + lrow) * K;

  float acc[2][2][4][4] = {};

  for (int k0 = 0; k0 < K; k0 += GBK) {
    #pragma unroll
    for (int half = 0; half < 2; ++half) {
      int kk = k0 + lk8 + half * 4;
      float4 av, bv;
      if (kk + 3 < K) {
        av = *(const float4*)(Arow + kk);
        bv = *(const float4*)(Wrow + kk);
      } else {
        float aa[4], bw[4];
        #pragma unroll
        for (int q = 0; q < 4; ++q) {
          aa[q] = (kk + q < K) ? Arow[kk + q] : 0.f;
          bw[q] = (kk + q < K) ? Wrow[kk + q] : 0.f;
        }
        av = make_float4(aa[0], aa[1], aa[2], aa[3]);
        bv = make_float4(bw[0], bw[1], bw[2], bw[3]);
      }
      int kb = lk8 + half * 4;
      As[kb + 0][lrow] = av.x; As[kb + 1][lrow] = av.y;
      As[kb + 2][lrow] = av.z; As[kb + 3][lrow] = av.w;
      Bs[kb + 0][lrow] = bv.x; Bs[kb + 1][lrow] = bv.y;
      Bs[kb + 2][lrow] = bv.z; Bs[kb + 3][lrow] = bv.w;
    }
    __syncthreads();

    #pragma unroll
    for (int k = 0; k < GBK; ++k) {
      float4 a0 = *(const float4*)&As[k][ty * 4];
      float4 a1 = *(const float4*)&As[k][64 + ty * 4];
      float4 b0 = *(const float4*)&Bs[k][tx * 4];
      float4 b1 = *(const float4*)&Bs[k][64 + tx * 4];
      float av_[2][4] = {{a0.x, a0.y, a0.z, a0.w}, {a1.x, a1.y, a1.z, a1.w}};
      float bv_[2][4] = {{b0.x, b0.y, b0.z, b0.w}, {b1.x, b1.y, b1.z, b1.w}};
      #pragma unroll
      for (int ra = 0; ra < 2; ++ra)
        #pragma unroll
        for (int rb = 0; rb < 2; ++rb)
          #pragma unroll
          for (int i = 0; i < 4; ++i)
            #pragma unroll
            for (int j = 0; j < 4; ++j)
              acc[ra][rb][i][j] += av_[ra][i] * bv_[rb][j];
    }
    __syncthreads();
  }

  #pragma unroll
  for (int ra = 0; ra < 2; ++ra)
    #pragma unroll
    for (int i = 0; i < 4; ++i) {
      int r = row0 + ra * 64 + ty * 4 + i;
      #pragma unroll
      for (int rb = 0; rb < 2; ++rb)
        #pragma unroll
        for (int j = 0; j < 4; ++j) {
          int cc = rb * 64 + tx * 4 + j;
          C[(size_t)r * 1024 + col0 + cc] = acc[ra][rb][i][j] + bias[wcol0 + cc];
        }
    }
}

// ---------------------------------------------------------------------------
// BiLSTM recurrence, 1024-thread K-split version.
// Block = (sample, dir). Wave w (0..15): half = w>>3 (K-half, wave-uniform so
// readlane lane indices stay uniform), row = (w&7)*64 + lane (gate row 0..511).
// Thread owns U[row, half*64 : half*64+64] = 16 float4 = 64 VGPRs — under the
// hard 128-VGPR cap of a 1024-thread block (4 waves/SIMD), so the allocator
// can keep it resident (previous 128-float/thread versions spilled: VGPR=76).
// half-1 partials (+ gate input, prefetched) combine via LDS psum.
// Nonlinearity on half-0 waves (gate = row>>7 is wave-uniform, branch-free);
// c/h update on tau<128. 3 barriers/step.
// ---------------------------------------------------------------------------
__global__ __launch_bounds__(1024) void lstm_kernel(
    const float* __restrict__ gates,
    const float* __restrict__ Uf, const float* __restrict__ Ub,
    float* __restrict__ h_seq)
{
  int blk = blockIdx.x;      // 0..127
  int b = blk & 63;
  int dir = blk >> 6;
  int tau = threadIdx.x;     // 0..1023
  int lane = tau & 63;
  int w = tau >> 6;          // 0..15
  int half = w >> 3;         // 0 or 1 (wave-uniform)
  int row = ((w & 7) << 6) | lane;   // 0..511 (PyTorch gate order i,f,g,o)
  int gate = row >> 7;               // wave-uniform (wave pair per gate)

  const float* U = dir ? Ub : Uf;
  const float4* Uchunk = (const float4*)(U + (size_t)row * Hq + (half << 6));

#define ULOAD(m) \
  float4 uv##m = Uchunk[m]; \
  asm volatile("" : "+v"(uv##m.x), "+v"(uv##m.y), "+v"(uv##m.z), "+v"(uv##m.w));
  ULOAD(0)  ULOAD(1)  ULOAD(2)  ULOAD(3)  ULOAD(4)  ULOAD(5)  ULOAD(6)  ULOAD(7)
  ULOAD(8)  ULOAD(9)  ULOAD(10) ULOAD(11) ULOAD(12) ULOAD(13) ULOAD(14) ULOAD(15)
#undef ULOAD

  __shared__ float h_sh[2][Hq];
  __shared__ float psum[512];
  __shared__ float nl_sh[512];
  if (tau < Hq) h_sh[0][tau] = 0.f;
  float c = 0.f;

  // half-1 threads carry the gate-input stream (adds into psum with partial)
  const float* gbase = gates + ((size_t)b * Lq) * 1024 + dir * 512 + row;
  float gcur = 0.f;
  if (half) gcur = gbase[(size_t)(dir ? (Lq - 1) : 0) * 1024];
  __syncthreads();

  for (int t = 0; t < Lq; ++t) {
    // prefetch next step's gate value (half-1 only; hidden under fma chain)
    float gnext = 0.f;
    if (half & (t + 1 < Lq)) {
      int ttn = dir ? (Lq - 2 - t) : (t + 1);
      gnext = gbase[(size_t)ttn * 1024];
    }

    // keep U pinned across the loop (0-instruction; biases RA against spill)
#define UPIN(m) asm volatile("" : "+v"(uv##m.x), "+v"(uv##m.y), "+v"(uv##m.z), "+v"(uv##m.w));
    UPIN(0)  UPIN(1)  UPIN(2)  UPIN(3)  UPIN(4)  UPIN(5)  UPIN(6)  UPIN(7)
    UPIN(8)  UPIN(9)  UPIN(10) UPIN(11) UPIN(12) UPIN(13) UPIN(14) UPIN(15)
#undef UPIN

    // cooperative h fetch: lane l of a half-h wave holds h[half*64 + l]
    int hvi = __float_as_int(h_sh[t & 1][(half << 6) + lane]);

    float a0 = 0.f, a1 = 0.f, a2 = 0.f, a3 = 0.f;
#define ACC(m) { \
    a0 = fmaf(__int_as_float(__builtin_amdgcn_readlane(hvi, 4*m + 0)), uv##m.x, a0); \
    a1 = fmaf(__int_as_float(__builtin_amdgcn_readlane(hvi, 4*m + 1)), uv##m.y, a1); \
    a2 = fmaf(__int_as_float(__builtin_amdgcn_readlane(hvi, 4*m + 2)), uv##m.z, a2); \
    a3 = fmaf(__int_as_float(__builtin_amdgcn_readlane(hvi, 4*m + 3)), uv##m.w, a3); }
    ACC(0)  ACC(1)  ACC(2)  ACC(3)  ACC(4)  ACC(5)  ACC(6)  ACC(7)
    ACC(8)  ACC(9)  ACC(10) ACC(11) ACC(12) ACC(13) ACC(14) ACC(15)
#undef ACC
    float partial = (a0 + a2) + (a1 + a3);

    if (half) psum[row] = partial + gcur;
    gcur = gnext;
    __syncthreads();                       // barrier 1: psum ready

    if (!half) {
      float g = partial + psum[row];
      // branch-free nonlinearity: sigmoid for i/f/o, tanh for g (one v_exp)
      bool isg = (gate == 2);
      float ax = fabsf(g);
      float arg = isg ? (-2.f * ax) : (-g);
      float e = __expf(arg);
      float inv = 1.f / (1.f + e);
      float r = isg ? (1.f - e) * inv : inv;
      nl_sh[row] = isg ? copysignf(r, g) : r;
    }
    __syncthreads();                       // barrier 2: nl ready

    if (tau < Hq) {
      float si = nl_sh[tau];
      float sf = nl_sh[tau + 128];
      float tg = nl_sh[tau + 256];
      float so = nl_sh[tau + 384];
      c = sf * c + si * tg;
      float h = so * tanh_fast(c);
      h_sh[(t & 1) ^ 1][tau] = h;
      int tt = dir ? (Lq - 1 - t) : t;
      h_seq[((size_t)b * Lq + tt) * 256 + dir * Hq + tau] = h;
    }
    __syncthreads();                       // barrier 3: h ready
  }
}

// ---------------------------------------------------------------------------
// GAT1 attention-score projections: s_src/s_trg[b,l,h] from proj1 [M,64]
// ---------------------------------------------------------------------------
__global__ void srctrg_kernel(const float* __restrict__ proj1,
                              const float* __restrict__ a_src,
                              const float* __restrict__ a_trg,
                              float* __restrict__ s_src, float* __restrict__ s_trg)
{
  int m = blockIdx.x * blockDim.x + threadIdx.x;
  if (m >= MQ) return;
  const float* p = proj1 + (size_t)m * 64;
  #pragma unroll
  for (int h = 0; h < 8; ++h) {
    float ss = 0.f, st = 0.f;
    #pragma unroll
    for (int f = 0; f < 8; ++f) {
      float v = p[h * 8 + f];
      ss += v * a_src[h * 8 + f];
      st += v * a_trg[h * 8 + f];
    }
    s_src[(size_t)m * 8 + h] = ss;
    s_trg[(size_t)m * 8 + h] = st;
  }
}

// ---------------------------------------------------------------------------
// GAT1 per-graph max: m1[b] = lrelu( max_h ( max_s src + max_t trg ) )
// ---------------------------------------------------------------------------
__global__ __launch_bounds__(256) void gat1max_kernel(
    const float* __restrict__ s_src, const float* __restrict__ s_trg,
    float* __restrict__ m1)
{
  int b = blockIdx.x;
  int tid = threadIdx.x;
  int h = tid >> 5, r = tid & 31;
  float ms = -3.4e38f, mt = -3.4e38f;
  for (int s = r; s < Lq; s += 32) {
    ms = fmaxf(ms, s_src[((size_t)b * Lq + s) * 8 + h]);
    mt = fmaxf(mt, s_trg[((size_t)b * Lq + s) * 8 + h]);
  }
  #pragma unroll
  for (int o = 16; o > 0; o >>= 1) {
    ms = fmaxf(ms, __shfl_xor(ms, o, 32));
    mt = fmaxf(mt, __shfl_xor(mt, o, 32));
  }
  __shared__ float hh[8];
  if (r == 0) hh[h] = ms + mt;
  __syncthreads();
  if (tid == 0) {
    float mm = -3.4e38f;
    #pragma unroll
    for (int k = 0; k < 8; ++k) mm = fmaxf(mm, hh[k]);
    m1[b] = lrelu(mm);
  }
}

// ---------------------------------------------------------------------------
// GAT1 aggregation: block per (b,h); thread per target t.
// ---------------------------------------------------------------------------
__global__ __launch_bounds__(256) void gat1_agg_kernel(
    const float* __restrict__ s_src, const float* __restrict__ s_trg,
    const float* __restrict__ proj1, const float* __restrict__ m1,
    const float* __restrict__ g1_b, float* __restrict__ h1)
{
  int b = blockIdx.x >> 3;
  int h = blockIdx.x & 7;
  int t = threadIdx.x;
  __shared__ float src_s[Lq], trg_s[Lq];
  __shared__ float proj_s[Lq * 8];

  size_t base = (size_t)b * Lq;
  src_s[t] = s_src[(base + t) * 8 + h];
  trg_s[t] = s_trg[(base + t) * 8 + h];
  {
    const float4* pr = (const float4*)(proj1 + (base + t) * 64 + h * 8);
    float4* psh = (float4*)(proj_s + t * 8);
    psh[0] = pr[0];
    psh[1] = pr[1];
  }
  __syncthreads();

  float m = m1[b];
  float mytrg = trg_s[t];
  float den = 1e-16f;
  float acc[8] = {};
  for (int s = 0; s < Lq; ++s) {
    float w = __expf(lrelu(src_s[s] + mytrg) - m);
    den += w;
    const float* ps = proj_s + s * 8;
    #pragma unroll
    for (int f = 0; f < 8; ++f) acc[f] += w * ps[f];
  }
  float inv = 1.f / den;
  float* out = h1 + (base + t) * 64 + h * 8;
  #pragma unroll
  for (int f = 0; f < 8; ++f) {
    float v = acc[f] * inv + g1_b[h * 8 + f];
    out[f] = v > 0.f ? v : expm1f(v);   // ELU
  }
}

// ---------------------------------------------------------------------------
// block reductions over 256 threads (4 waves of 64)
// ---------------------------------------------------------------------------
__device__ __forceinline__ float block_max_256(float v, volatile float* red) {
  #pragma unroll
  for (int o = 32; o > 0; o >>= 1) v = fmaxf(v, __shfl_xor(v, o, 64));
  int tid = threadIdx.x;
  if ((tid & 63) == 0) red[tid >> 6] = v;
  __syncthreads();
  float r = fmaxf(fmaxf(red[0], red[1]), fmaxf(red[2], red[3]));
  __syncthreads();
  return r;
}
__device__ __forceinline__ float block_sum_256(float v, volatile float* red) {
  #pragma unroll
  for (int o = 32; o > 0; o >>= 1) v += __shfl_xor(v, o, 64);
  int tid = threadIdx.x;
  if ((tid & 63) == 0) red[tid >> 6] = v;
  __syncthreads();
  float r = red[0] + red[1] + red[2] + red[3];
  __syncthreads();
  return r;
}

// ---------------------------------------------------------------------------
// GAT2 (1 head, 1 feat) -> att weights -> softmax -> weighted-max pooling.
// ---------------------------------------------------------------------------
__global__ __launch_bounds__(256) void gat2_att_pool_kernel(
    const float* __restrict__ h1, const float* __restrict__ g2_W,
    const float* __restrict__ g2_src, const float* __restrict__ g2_trg,
    const float* __restrict__ ctx, const float* __restrict__ h_seq,
    float* __restrict__ att_out, float* __restrict__ pooled)
{
  int b = blockIdx.x;
  int tid = threadIdx.x;
  __shared__ float w2[64];
  __shared__ float src2[Lq], trg2[Lq], dq[Lq], att_sh[Lq];
  __shared__ float red[4];

  if (tid < 64) w2[tid] = g2_W[tid];
  __syncthreads();

  const float* hr = h1 + ((size_t)b * Lq + tid) * 64;
  float p = 0.f;
  #pragma unroll
  for (int k = 0; k < 64; ++k) p += hr[k] * w2[k];
  float a_s = g2_src[0], a_t = g2_trg[0];
  src2[tid] = p * a_s;
  trg2[tid] = p * a_t;
  __syncthreads();

  float ms = block_max_256(src2[tid], red);
  float mt = block_max_256(trg2[tid], red);
  float m2 = lrelu(ms + mt);

  float mytrg = trg2[tid];
  float den = 1e-16f;
  for (int s = 0; s < Lq; ++s)
    den += __expf(lrelu(src2[s] + mytrg) - m2);
  dq[tid] = ctx[tid] / den;
  __syncthreads();

  float mysrc = src2[tid];
  float raw = 0.f;
  for (int t = 0; t < Lq; ++t)
    raw += dq[t] * __expf(lrelu(mysrc + trg2[t]) - m2);

  float mr = block_max_256(raw, red);
  float e = __expf(raw - mr);
  float ssum = block_sum_256(e, red);
  float att = e / ssum;
  att_out[(size_t)b * Lq + tid] = att;
  att_sh[tid] = att;
  __syncthreads();

  float pm = -3.4e38f;
  for (int l = 0; l < Lq; ++l)
    pm = fmaxf(pm, h_seq[((size_t)b * Lq + l) * 256 + tid] * att_sh[l]);
  pooled[(size_t)b * 256 + tid] = pm;
}

// ---------------------------------------------------------------------------
// Head: grid(64) — one block per sample (was a single serial block).
// ---------------------------------------------------------------------------
__global__ __launch_bounds__(256) void head_kernel(
    const float* __restrict__ pooled, const float* __restrict__ lin_W,
    const float* __restrict__ lin_b, const float* __restrict__ out_W,
    const float* __restrict__ out_b, float* __restrict__ logits)
{
  int i = blockIdx.x;
  int tid = threadIdx.x;
  int j = tid & 63, kq = tid >> 6;   // 4 k-chunks of 64
  __shared__ float part[4][64];
  __shared__ float hcl[64];
  const float* pr = pooled + i * 256 + kq * 64;
  const float* wr = lin_W + j * 256 + kq * 64;
  float d = 0.f;
  #pragma unroll
  for (int k = 0; k < 64; ++k) d += pr[k] * wr[k];
  part[kq][j] = d;
  __syncthreads();
  if (tid < 64) {
    float v = part[0][j] + part[1][j] + part[2][j] + part[3][j] + lin_b[j];
    hcl[j] = fmaxf(v, 0.f);
  }
  __syncthreads();
  if (tid < 128) {
    int cc = tid >> 6, jj = tid & 63;
    float p = hcl[jj] * out_W[cc * 64 + jj];
    #pragma unroll
    for (int o = 32; o > 0; o >>= 1) p += __shfl_xor(p, o, 64);
    if (jj == 0) logits[i * 2 + cc] = p + out_b[cc];
  }
}

// ---------------------------------------------------------------------------
extern "C" void kernel_launch(void* const* d_in, const int* in_sizes, int n_in,
                              void* d_out, int out_size, void* d_ws, size_t ws_size,
                              hipStream_t stream)
{
  const int*   ids    = (const int*)  d_in[0];
  // d_in[1] = attention_mask (all ones by construction; unused)
  const float* emb    = (const float*)d_in[2];
  const float* Wih_f  = (const float*)d_in[3];
  const float* Whh_f  = (const float*)d_in[4];
  const float* b_f    = (const float*)d_in[5];
  const float* Wih_b  = (const float*)d_in[6];
  const float* Whh_b  = (const float*)d_in[7];
  const float* b_b    = (const float*)d_in[8];
  const float* g1_W   = (const float*)d_in[9];
  const float* g1_src = (const float*)d_in[10];
  const float* g1_trg = (const float*)d_in[11];
  const float* g1_b   = (const float*)d_in[12];
  const float* g2_W   = (const float*)d_in[13];
  const float* g2_src = (const float*)d_in[14];
  const float* g2_trg = (const float*)d_in[15];
  // d_in[16] = g2_b (unused)
  const float* ctx    = (const float*)d_in[17];
  const float* lin_W  = (const float*)d_in[18];
  const float* lin_b  = (const float*)d_in[19];
  const float* out_W  = (const float*)d_in[20];
  const float* out_b  = (const float*)d_in[21];

  float* out_f   = (float*)d_out;
  float* logits  = out_f;          // [64,2]
  float* att_out = out_f + 128;    // [64,256]

  float* ws = (float*)d_ws;
  const size_t M = MQ;
  float* gates   = ws; ws += M * 1024;   // [M][1024] fwd|bwd
  float* h_seq   = ws; ws += M * 256;
  float* proj1   = ws; ws += M * 64;
  float* s_src   = ws; ws += M * 8;
  float* s_trg   = ws; ws += M * 8;
  float* h1      = ws; ws += M * 64;
  float* m1      = ws; ws += 64;
  float* pooled  = ws; ws += 64 * 256;

  dim3 thr(256);

  // Stage A: fused embedding-gather + both input-gate GEMMs (K=300, N=1024)
  gemm_gates<<<dim3(MQ / GBM, 1024 / GBN), thr, 0, stream>>>(emb, ids, Wih_f, b_f, Wih_b, b_b, gates);

  // Stage B: BiLSTM recurrence (1024-thread K-split blocks)
  lstm_kernel<<<128, 1024, 0, stream>>>(gates, Whh_f, Whh_b, h_seq);

  // Stage C: GAT layer 1
  gemm_awt<<<dim3(MQ / BM, 1), thr, 0, stream>>>(h_seq, nullptr, g1_W, nullptr, proj1, MQ, 64, 256);
  srctrg_kernel<<<MQ / 256, thr, 0, stream>>>(proj1, g1_src, g1_trg, s_src, s_trg);
  gat1max_kernel<<<Bq, thr, 0, stream>>>(s_src, s_trg, m1);
  gat1_agg_kernel<<<Bq * 8, thr, 0, stream>>>(s_src, s_trg, proj1, m1, g1_b, h1);

  // Stage D: GAT layer 2 attention -> context attention -> softmax -> pooling
  gat2_att_pool_kernel<<<Bq, thr, 0, stream>>>(h1, g2_W, g2_src, g2_trg, ctx, h_seq, att_out, pooled);

  // Stage E: classifier head
  head_kernel<<<64, thr, 0, stream>>>(pooled, lin_W, lin_b, out_W, out_b, logits);
}

// Round 6
// 521.827 us; speedup vs baseline: 1.3491x; 1.1463x over previous
//
#include <hip/hip_runtime.h>
#include <math.h>

#define Bq 64
#define Lq 256
#define Eq 300
#define Hq 128
#define MQ (Bq*Lq)   // 16384

#define LRELU_S 0.2f

typedef float f32x4 __attribute__((ext_vector_type(4)));

__device__ __forceinline__ float lrelu(float x) { return x > 0.f ? x : LRELU_S * x; }

// call-free tanh: one v_exp + div, exact sign/saturation behavior
__device__ __forceinline__ float tanh_fast(float x) {
  float ax = fabsf(x);
  float e = __expf(-2.f * ax);          // (0,1], never overflows
  float r = (1.f - e) / (1.f + e);
  return copysignf(r, x);
}

// ---------------------------------------------------------------------------
// Generic tiled GEMM: C[m,n] = sum_k A[m,k]*W[n,k] (+ bias[n])
// ---------------------------------------------------------------------------
#define BM 64
#define BN 64
#define BK 16

__global__ __launch_bounds__(256) void gemm_awt(
    const float* __restrict__ Asrc, const int* __restrict__ ids,
    const float* __restrict__ W, const float* __restrict__ bias,
    float* __restrict__ C, int M, int N, int K)
{
  __shared__ float As[BK][BM + 4];
  __shared__ float Bs[BK][BN + 4];
  int tid = threadIdx.x;
  int tx = tid & 15, ty = tid >> 4;
  int row0 = blockIdx.x * BM, col0 = blockIdx.y * BN;

  int lrow = tid >> 2;          // 0..63
  int lk   = (tid & 3) << 2;    // 0,4,8,12

  const float* Arow;
  {
    int r = row0 + lrow;
    int id = ids ? ids[r] : r;
    Arow = Asrc + (size_t)id * K;
  }
  const float* Wrow = W + (size_t)(col0 + lrow) * K;

  float acc[4][4] = {};

  for (int k0 = 0; k0 < K; k0 += BK) {
    int kk = k0 + lk;
    float4 av, bv;
    if (kk + 3 < K) {
      av = *(const float4*)(Arow + kk);
      bv = *(const float4*)(Wrow + kk);
    } else {
      float a0 = (kk + 0 < K) ? Arow[kk + 0] : 0.f;
      float a1 = (kk + 1 < K) ? Arow[kk + 1] : 0.f;
      float a2 = (kk + 2 < K) ? Arow[kk + 2] : 0.f;
      float a3 = (kk + 3 < K) ? Arow[kk + 3] : 0.f;
      av = make_float4(a0, a1, a2, a3);
      float b0 = (kk + 0 < K) ? Wrow[kk + 0] : 0.f;
      float b1 = (kk + 1 < K) ? Wrow[kk + 1] : 0.f;
      float b2 = (kk + 2 < K) ? Wrow[kk + 2] : 0.f;
      float b3 = (kk + 3 < K) ? Wrow[kk + 3] : 0.f;
      bv = make_float4(b0, b1, b2, b3);
    }
    As[lk + 0][lrow] = av.x; As[lk + 1][lrow] = av.y;
    As[lk + 2][lrow] = av.z; As[lk + 3][lrow] = av.w;
    Bs[lk + 0][lrow] = bv.x; Bs[lk + 1][lrow] = bv.y;
    Bs[lk + 2][lrow] = bv.z; Bs[lk + 3][lrow] = bv.w;
    __syncthreads();

    #pragma unroll
    for (int k = 0; k < BK; ++k) {
      float4 a4 = *(const float4*)&As[k][ty * 4];
      float4 b4 = *(const float4*)&Bs[k][tx * 4];
      float a[4] = {a4.x, a4.y, a4.z, a4.w};
      float bb[4] = {b4.x, b4.y, b4.z, b4.w};
      #pragma unroll
      for (int i = 0; i < 4; ++i)
        #pragma unroll
        for (int j = 0; j < 4; ++j)
          acc[i][j] += a[i] * bb[j];
    }
    __syncthreads();
  }

  #pragma unroll
  for (int i = 0; i < 4; ++i) {
    int r = row0 + ty * 4 + i;
    #pragma unroll
    for (int j = 0; j < 4; ++j) {
      int cidx = col0 + tx * 4 + j;
      float v = acc[i][j] + (bias ? bias[cidx] : 0.f);
      C[(size_t)r * N + cidx] = v;
    }
  }
}

// ---------------------------------------------------------------------------
// Fused gates GEMM, 128x128 tile: C[m, 0:512] = emb[ids[m]] @ Wih_f^T + b_f
//                                 C[m, 512:1024] = emb[ids[m]] @ Wih_b^T + b_b
// ---------------------------------------------------------------------------
#define GBM 128
#define GBN 128
#define GBK 16

__global__ __launch_bounds__(256) void gemm_gates(
    const float* __restrict__ emb, const int* __restrict__ ids,
    const float* __restrict__ Wf, const float* __restrict__ bf,
    const float* __restrict__ Wb, const float* __restrict__ bb_,
    float* __restrict__ C)
{
  const int K = Eq;  // 300
  __shared__ float As[GBK][GBM + 4];
  __shared__ float Bs[GBK][GBN + 4];
  int tid = threadIdx.x;
  int tx = tid & 15, ty = tid >> 4;
  int row0 = blockIdx.x * GBM;
  int col0 = blockIdx.y * GBN;          // 0..896; 128 | 512 so one half per block
  const float* W    = (col0 < 512) ? Wf : Wb;
  const float* bias = (col0 < 512) ? bf : bb_;
  int wcol0 = col0 & 511;

  int lrow = tid >> 1;          // 0..127
  int lk8  = (tid & 1) << 3;    // 0 or 8

  const float* Arow = emb + (size_t)ids[row0 + lrow] * K;
  const float* Wrow = W + (size_t)(wcol0 + lrow) * K;

  float acc[2][2][4][4] = {};

  for (int k0 = 0; k0 < K; k0 += GBK) {
    #pragma unroll
    for (int half = 0; half < 2; ++half) {
      int kk = k0 + lk8 + half * 4;
      float4 av, bv;
      if (kk + 3 < K) {
        av = *(const float4*)(Arow + kk);
        bv = *(const float4*)(Wrow + kk);
      } else {
        float aa[4], bw[4];
        #pragma unroll
        for (int q = 0; q < 4; ++q) {
          aa[q] = (kk + q < K) ? Arow[kk + q] : 0.f;
          bw[q] = (kk + q < K) ? Wrow[kk + q] : 0.f;
        }
        av = make_float4(aa[0], aa[1], aa[2], aa[3]);
        bv = make_float4(bw[0], bw[1], bw[2], bw[3]);
      }
      int kb = lk8 + half * 4;
      As[kb + 0][lrow] = av.x; As[kb + 1][lrow] = av.y;
      As[kb + 2][lrow] = av.z; As[kb + 3][lrow] = av.w;
      Bs[kb + 0][lrow] = bv.x; Bs[kb + 1][lrow] = bv.y;
      Bs[kb + 2][lrow] = bv.z; Bs[kb + 3][lrow] = bv.w;
    }
    __syncthreads();

    #pragma unroll
    for (int k = 0; k < GBK; ++k) {
      float4 a0 = *(const float4*)&As[k][ty * 4];
      float4 a1 = *(const float4*)&As[k][64 + ty * 4];
      float4 b0 = *(const float4*)&Bs[k][tx * 4];
      float4 b1 = *(const float4*)&Bs[k][64 + tx * 4];
      float av_[2][4] = {{a0.x, a0.y, a0.z, a0.w}, {a1.x, a1.y, a1.z, a1.w}};
      float bv_[2][4] = {{b0.x, b0.y, b0.z, b0.w}, {b1.x, b1.y, b1.z, b1.w}};
      #pragma unroll
      for (int ra = 0; ra < 2; ++ra)
        #pragma unroll
        for (int rb = 0; rb < 2; ++rb)
          #pragma unroll
          for (int i = 0; i < 4; ++i)
            #pragma unroll
            for (int j = 0; j < 4; ++j)
              acc[ra][rb][i][j] += av_[ra][i] * bv_[rb][j];
    }
    __syncthreads();
  }

  #pragma unroll
  for (int ra = 0; ra < 2; ++ra)
    #pragma unroll
    for (int i = 0; i < 4; ++i) {
      int r = row0 + ra * 64 + ty * 4 + i;
      #pragma unroll
      for (int rb = 0; rb < 2; ++rb)
        #pragma unroll
        for (int j = 0; j < 4; ++j) {
          int cc = rb * 64 + tx * 4 + j;
          C[(size_t)r * 1024 + col0 + cc] = acc[ra][rb][i][j] + bias[wcol0 + cc];
        }
    }
}

// ---------------------------------------------------------------------------
// BiLSTM recurrence. One block per (sample, direction), 512 threads.
// Row mapping: wave w, lane l -> gate = (l>>4)&3, hidx = 16w + (l&15),
// row = gate*128 + hidx. Gate exchange via 4 __shfl, 1 barrier/step.
// U row = 32 native f32x4 values, all 32 named in ONE asm statement per
// iteration (mega-pin): forces 128 VGPRs simultaneously live at that point,
// so spilling costs 32 b128 reload/store per step — strictly worse than
// residency (~160 regs fits the 2-wave/SIMD budget of 256). Rounds 1-4 used
// per-value pins; the allocator split live ranges between them (VGPR=44..76,
// ~2000 cyc/step of L1/L2 re-fetch, invisible in FETCH_SIZE since it hits L2).
// ---------------------------------------------------------------------------
__global__ __launch_bounds__(512, 1) void lstm_kernel(
    const float* __restrict__ gates,
    const float* __restrict__ Uf, const float* __restrict__ Ub,
    float* __restrict__ h_seq)
{
  int blk = blockIdx.x;      // 0..127
  int b = blk & 63;
  int dir = blk >> 6;
  int j = threadIdx.x;       // 0..511
  int lane = j & 63;
  int w = j >> 6;            // wave 0..7
  int gate = (lane >> 4) & 3;          // 0:i 1:f 2:g 3:o
  int hidx = (w << 4) | (lane & 15);   // 0..127
  int row = (gate << 7) | hidx;        // 0..511

  const float* U = dir ? Ub : Uf;
  const f32x4* Urow = (const f32x4*)(U + (size_t)row * Hq);

#define UDECL(m) f32x4 u##m = Urow[m];
  UDECL(0)  UDECL(1)  UDECL(2)  UDECL(3)  UDECL(4)  UDECL(5)  UDECL(6)  UDECL(7)
  UDECL(8)  UDECL(9)  UDECL(10) UDECL(11) UDECL(12) UDECL(13) UDECL(14) UDECL(15)
  UDECL(16) UDECL(17) UDECL(18) UDECL(19) UDECL(20) UDECL(21) UDECL(22) UDECL(23)
  UDECL(24) UDECL(25) UDECL(26) UDECL(27) UDECL(28) UDECL(29) UDECL(30) UDECL(31)
#undef UDECL

#define MEGAPIN() asm volatile("" : \
  "+v"(u0),"+v"(u1),"+v"(u2),"+v"(u3),"+v"(u4),"+v"(u5),"+v"(u6),"+v"(u7), \
  "+v"(u8),"+v"(u9),"+v"(u10),"+v"(u11),"+v"(u12),"+v"(u13),"+v"(u14),"+v"(u15), \
  "+v"(u16),"+v"(u17),"+v"(u18),"+v"(u19),"+v"(u20),"+v"(u21),"+v"(u22),"+v"(u23), \
  "+v"(u24),"+v"(u25),"+v"(u26),"+v"(u27),"+v"(u28),"+v"(u29),"+v"(u30),"+v"(u31))

  __shared__ __align__(16) float h_sh[2][Hq];
  if (j < Hq) h_sh[0][j] = 0.f;
  float c = 0.f;

  const float* gbase = gates + ((size_t)b * Lq) * 1024 + dir * 512 + row;
  int tt0 = dir ? (Lq - 1) : 0;
  float gcur = gbase[(size_t)tt0 * 1024];
  __syncthreads();

  for (int t = 0; t < Lq; ++t) {
    MEGAPIN();   // all 128 U floats forced live HERE, every iteration

    // prefetch next step's gate value (latency hidden under the fma chain)
    float gnext = 0.f;
    int tn = t + 1;
    if (tn < Lq) {
      int ttn = dir ? (Lq - 1 - tn) : tn;
      gnext = gbase[(size_t)ttn * 1024];
    }

    // cooperative h fetch: lane m holds h[2m], h[2m+1]
    float2 hp = *(const float2*)(&h_sh[t & 1][lane * 2]);
    int hx = __float_as_int(hp.x);
    int hy = __float_as_int(hp.y);

    float a0 = 0.f, a1 = 0.f, a2 = 0.f, a3 = 0.f;
#define ACC(m) { \
    a0 = fmaf(__int_as_float(__builtin_amdgcn_readlane(hx, 2*(m)  )), u##m[0], a0); \
    a1 = fmaf(__int_as_float(__builtin_amdgcn_readlane(hy, 2*(m)  )), u##m[1], a1); \
    a2 = fmaf(__int_as_float(__builtin_amdgcn_readlane(hx, 2*(m)+1)), u##m[2], a2); \
    a3 = fmaf(__int_as_float(__builtin_amdgcn_readlane(hy, 2*(m)+1)), u##m[3], a3); }
    ACC(0)  ACC(1)  ACC(2)  ACC(3)  ACC(4)  ACC(5)  ACC(6)  ACC(7)
    ACC(8)  ACC(9)  ACC(10) ACC(11) ACC(12) ACC(13) ACC(14) ACC(15)
    ACC(16) ACC(17) ACC(18) ACC(19) ACC(20) ACC(21) ACC(22) ACC(23)
    ACC(24) ACC(25) ACC(26) ACC(27) ACC(28) ACC(29) ACC(30) ACC(31)
#undef ACC

    float g = gcur + ((a0 + a2) + (a1 + a3));
    gcur = gnext;

    // branch-free nonlinearity: sigmoid for i/f/o, tanh for g. One v_exp each.
    bool isg = (gate == 2);
    float ax = fabsf(g);
    float arg = isg ? (-2.f * ax) : (-g);
    float e = __expf(arg);
    float inv = 1.f / (1.f + e);
    float r = isg ? (1.f - e) * inv : inv;
    float nl = isg ? copysignf(r, g) : r;

    // in-wave gate exchange: lanes {base, base+16, base+32, base+48} hold
    // i,f,g,o for the same hidx
    int base = lane & 15;
    float si = __shfl(nl, base,      64);
    float sf = __shfl(nl, base + 16, 64);
    float tg = __shfl(nl, base + 32, 64);
    float so = __shfl(nl, base + 48, 64);
    c = sf * c + si * tg;             // redundant across the 4 gate groups
    float h = so * tanh_fast(c);

    if (lane < 16) {
      h_sh[(t & 1) ^ 1][hidx] = h;
      int tt = dir ? (Lq - 1 - t) : t;
      h_seq[((size_t)b * Lq + tt) * 256 + dir * Hq + hidx] = h;
    }
    __syncthreads();
  }
#undef MEGAPIN
}

// ---------------------------------------------------------------------------
// GAT1 attention-score projections: s_src/s_trg[b,l,h] from proj1 [M,64]
// ---------------------------------------------------------------------------
__global__ void srctrg_kernel(const float* __restrict__ proj1,
                              const float* __restrict__ a_src,
                              const float* __restrict__ a_trg,
                              float* __restrict__ s_src, float* __restrict__ s_trg)
{
  int m = blockIdx.x * blockDim.x + threadIdx.x;
  if (m >= MQ) return;
  const float* p = proj1 + (size_t)m * 64;
  #pragma unroll
  for (int h = 0; h < 8; ++h) {
    float ss = 0.f, st = 0.f;
    #pragma unroll
    for (int f = 0; f < 8; ++f) {
      float v = p[h * 8 + f];
      ss += v * a_src[h * 8 + f];
      st += v * a_trg[h * 8 + f];
    }
    s_src[(size_t)m * 8 + h] = ss;
    s_trg[(size_t)m * 8 + h] = st;
  }
}

// ---------------------------------------------------------------------------
// GAT1 per-graph max: m1[b] = lrelu( max_h ( max_s src + max_t trg ) )
// ---------------------------------------------------------------------------
__global__ __launch_bounds__(256) void gat1max_kernel(
    const float* __restrict__ s_src, const float* __restrict__ s_trg,
    float* __restrict__ m1)
{
  int b = blockIdx.x;
  int tid = threadIdx.x;
  int h = tid >> 5, r = tid & 31;
  float ms = -3.4e38f, mt = -3.4e38f;
  for (int s = r; s < Lq; s += 32) {
    ms = fmaxf(ms, s_src[((size_t)b * Lq + s) * 8 + h]);
    mt = fmaxf(mt, s_trg[((size_t)b * Lq + s) * 8 + h]);
  }
  #pragma unroll
  for (int o = 16; o > 0; o >>= 1) {
    ms = fmaxf(ms, __shfl_xor(ms, o, 32));
    mt = fmaxf(mt, __shfl_xor(mt, o, 32));
  }
  __shared__ float hh[8];
  if (r == 0) hh[h] = ms + mt;
  __syncthreads();
  if (tid == 0) {
    float mm = -3.4e38f;
    #pragma unroll
    for (int k = 0; k < 8; ++k) mm = fmaxf(mm, hh[k]);
    m1[b] = lrelu(mm);
  }
}

// ---------------------------------------------------------------------------
// GAT1 aggregation: block per (b,h); thread per target t.
// ---------------------------------------------------------------------------
__global__ __launch_bounds__(256) void gat1_agg_kernel(
    const float* __restrict__ s_src, const float* __restrict__ s_trg,
    const float* __restrict__ proj1, const float* __restrict__ m1,
    const float* __restrict__ g1_b, float* __restrict__ h1)
{
  int b = blockIdx.x >> 3;
  int h = blockIdx.x & 7;
  int t = threadIdx.x;
  __shared__ float src_s[Lq], trg_s[Lq];
  __shared__ float proj_s[Lq * 8];

  size_t base = (size_t)b * Lq;
  src_s[t] = s_src[(base + t) * 8 + h];
  trg_s[t] = s_trg[(base + t) * 8 + h];
  {
    const float4* pr = (const float4*)(proj1 + (base + t) * 64 + h * 8);
    float4* psh = (float4*)(proj_s + t * 8);
    psh[0] = pr[0];
    psh[1] = pr[1];
  }
  __syncthreads();

  float m = m1[b];
  float mytrg = trg_s[t];
  float den = 1e-16f;
  float acc[8] = {};
  for (int s = 0; s < Lq; ++s) {
    float w = __expf(lrelu(src_s[s] + mytrg) - m);
    den += w;
    const float* ps = proj_s + s * 8;
    #pragma unroll
    for (int f = 0; f < 8; ++f) acc[f] += w * ps[f];
  }
  float inv = 1.f / den;
  float* out = h1 + (base + t) * 64 + h * 8;
  #pragma unroll
  for (int f = 0; f < 8; ++f) {
    float v = acc[f] * inv + g1_b[h * 8 + f];
    out[f] = v > 0.f ? v : expm1f(v);   // ELU
  }
}

// ---------------------------------------------------------------------------
// block reductions over 256 threads (4 waves of 64)
// ---------------------------------------------------------------------------
__device__ __forceinline__ float block_max_256(float v, volatile float* red) {
  #pragma unroll
  for (int o = 32; o > 0; o >>= 1) v = fmaxf(v, __shfl_xor(v, o, 64));
  int tid = threadIdx.x;
  if ((tid & 63) == 0) red[tid >> 6] = v;
  __syncthreads();
  float r = fmaxf(fmaxf(red[0], red[1]), fmaxf(red[2], red[3]));
  __syncthreads();
  return r;
}
__device__ __forceinline__ float block_sum_256(float v, volatile float* red) {
  #pragma unroll
  for (int o = 32; o > 0; o >>= 1) v += __shfl_xor(v, o, 64);
  int tid = threadIdx.x;
  if ((tid & 63) == 0) red[tid >> 6] = v;
  __syncthreads();
  float r = red[0] + red[1] + red[2] + red[3];
  __syncthreads();
  return r;
}

// ---------------------------------------------------------------------------
// GAT2 (1 head, 1 feat) -> att weights -> softmax -> weighted-max pooling.
// ---------------------------------------------------------------------------
__global__ __launch_bounds__(256) void gat2_att_pool_kernel(
    const float* __restrict__ h1, const float* __restrict__ g2_W,
    const float* __restrict__ g2_src, const float* __restrict__ g2_trg,
    const float* __restrict__ ctx, const float* __restrict__ h_seq,
    float* __restrict__ att_out, float* __restrict__ pooled)
{
  int b = blockIdx.x;
  int tid = threadIdx.x;
  __shared__ float w2[64];
  __shared__ float src2[Lq], trg2[Lq], dq[Lq], att_sh[Lq];
  __shared__ float red[4];

  if (tid < 64) w2[tid] = g2_W[tid];
  __syncthreads();

  const float* hr = h1 + ((size_t)b * Lq + tid) * 64;
  float p = 0.f;
  #pragma unroll
  for (int k = 0; k < 64; ++k) p += hr[k] * w2[k];
  float a_s = g2_src[0], a_t = g2_trg[0];
  src2[tid] = p * a_s;
  trg2[tid] = p * a_t;
  __syncthreads();

  float ms = block_max_256(src2[tid], red);
  float mt = block_max_256(trg2[tid], red);
  float m2 = lrelu(ms + mt);

  float mytrg = trg2[tid];
  float den = 1e-16f;
  for (int s = 0; s < Lq; ++s)
    den += __expf(lrelu(src2[s] + mytrg) - m2);
  dq[tid] = ctx[tid] / den;
  __syncthreads();

  float mysrc = src2[tid];
  float raw = 0.f;
  for (int t = 0; t < Lq; ++t)
    raw += dq[t] * __expf(lrelu(mysrc + trg2[t]) - m2);

  float mr = block_max_256(raw, red);
  float e = __expf(raw - mr);
  float ssum = block_sum_256(e, red);
  float att = e / ssum;
  att_out[(size_t)b * Lq + tid] = att;
  att_sh[tid] = att;
  __syncthreads();

  float pm = -3.4e38f;
  for (int l = 0; l < Lq; ++l)
    pm = fmaxf(pm, h_seq[((size_t)b * Lq + l) * 256 + tid] * att_sh[l]);
  pooled[(size_t)b * 256 + tid] = pm;
}

// ---------------------------------------------------------------------------
// Head: grid(64) — one block per sample.
// ---------------------------------------------------------------------------
__global__ __launch_bounds__(256) void head_kernel(
    const float* __restrict__ pooled, const float* __restrict__ lin_W,
    const float* __restrict__ lin_b, const float* __restrict__ out_W,
    const float* __restrict__ out_b, float* __restrict__ logits)
{
  int i = blockIdx.x;
  int tid = threadIdx.x;
  int j = tid & 63, kq = tid >> 6;   // 4 k-chunks of 64
  __shared__ float part[4][64];
  __shared__ float hcl[64];
  const float* pr = pooled + i * 256 + kq * 64;
  const float* wr = lin_W + j * 256 + kq * 64;
  float d = 0.f;
  #pragma unroll
  for (int k = 0; k < 64; ++k) d += pr[k] * wr[k];
  part[kq][j] = d;
  __syncthreads();
  if (tid < 64) {
    float v = part[0][j] + part[1][j] + part[2][j] + part[3][j] + lin_b[j];
    hcl[j] = fmaxf(v, 0.f);
  }
  __syncthreads();
  if (tid < 128) {
    int cc = tid >> 6, jj = tid & 63;
    float p = hcl[jj] * out_W[cc * 64 + jj];
    #pragma unroll
    for (int o = 32; o > 0; o >>= 1) p += __shfl_xor(p, o, 64);
    if (jj == 0) logits[i * 2 + cc] = p + out_b[cc];
  }
}

// ---------------------------------------------------------------------------
extern "C" void kernel_launch(void* const* d_in, const int* in_sizes, int n_in,
                              void* d_out, int out_size, void* d_ws, size_t ws_size,
                              hipStream_t stream)
{
  const int*   ids    = (const int*)  d_in[0];
  // d_in[1] = attention_mask (all ones by construction; unused)
  const float* emb    = (const float*)d_in[2];
  const float* Wih_f  = (const float*)d_in[3];
  const float* Whh_f  = (const float*)d_in[4];
  const float* b_f    = (const float*)d_in[5];
  const float* Wih_b  = (const float*)d_in[6];
  const float* Whh_b  = (const float*)d_in[7];
  const float* b_b    = (const float*)d_in[8];
  const float* g1_W   = (const float*)d_in[9];
  const float* g1_src = (const float*)d_in[10];
  const float* g1_trg = (const float*)d_in[11];
  const float* g1_b   = (const float*)d_in[12];
  const float* g2_W   = (const float*)d_in[13];
  const float* g2_src = (const float*)d_in[14];
  const float* g2_trg = (const float*)d_in[15];
  // d_in[16] = g2_b (unused)
  const float* ctx    = (const float*)d_in[17];
  const float* lin_W  = (const float*)d_in[18];
  const float* lin_b  = (const float*)d_in[19];
  const float* out_W  = (const float*)d_in[20];
  const float* out_b  = (const float*)d_in[21];

  float* out_f   = (float*)d_out;
  float* logits  = out_f;          // [64,2]
  float* att_out = out_f + 128;    // [64,256]

  float* ws = (float*)d_ws;
  const size_t M = MQ;
  float* gates   = ws; ws += M * 1024;   // [M][1024] fwd|bwd
  float* h_seq   = ws; ws += M * 256;
  float* proj1   = ws; ws += M * 64;
  float* s_src   = ws; ws += M * 8;
  float* s_trg   = ws; ws += M * 8;
  float* h1      = ws; ws += M * 64;
  float* m1      = ws; ws += 64;
  float* pooled  = ws; ws += 64 * 256;

  dim3 thr(256);

  // Stage A: fused embedding-gather + both input-gate GEMMs (K=300, N=1024)
  gemm_gates<<<dim3(MQ / GBM, 1024 / GBN), thr, 0, stream>>>(emb, ids, Wih_f, b_f, Wih_b, b_b, gates);

  // Stage B: BiLSTM recurrence
  lstm_kernel<<<128, 512, 0, stream>>>(gates, Whh_f, Whh_b, h_seq);

  // Stage C: GAT layer 1
  gemm_awt<<<dim3(MQ / BM, 1), thr, 0, stream>>>(h_seq, nullptr, g1_W, nullptr, proj1, MQ, 64, 256);
  srctrg_kernel<<<MQ / 256, thr, 0, stream>>>(proj1, g1_src, g1_trg, s_src, s_trg);
  gat1max_kernel<<<Bq, thr, 0, stream>>>(s_src, s_trg, m1);
  gat1_agg_kernel<<<Bq * 8, thr, 0, stream>>>(s_src, s_trg, proj1, m1, g1_b, h1);

  // Stage D: GAT layer 2 attention -> context attention -> softmax -> pooling
  gat2_att_pool_kernel<<<Bq, thr, 0, stream>>>(h1, g2_W, g2_src, g2_trg, ctx, h_seq, att_out, pooled);

  // Stage E: classifier head
  head_kernel<<<64, thr, 0, stream>>>(pooled, lin_W, lin_b, out_W, out_b, logits);
}